// Round 1
// 897.713 us; speedup vs baseline: 1.0998x; 1.0998x over previous
//
#include <hip/hip_runtime.h>

#define NN 50000
#define NE 640000
#define DD 128

typedef float f32x4 __attribute__((ext_vector_type(4)));
typedef __bf16 bf16x8 __attribute__((ext_vector_type(8)));
typedef unsigned short u16x8 __attribute__((ext_vector_type(8)));

__device__ inline __bf16 f2bf(float f) {
  unsigned u = __builtin_bit_cast(unsigned, f);
  u = (u + 0x7fffu + ((u >> 16) & 1u)) >> 16;
  unsigned short h = (unsigned short)u;
  return __builtin_bit_cast(__bf16, h);
}
__device__ inline unsigned short f2bfu(float f) {
  return __builtin_bit_cast(unsigned short, f2bf(f));
}
__device__ inline float bf2f(unsigned bits16) {
  return __builtin_bit_cast(float, bits16 << 16);
}
__device__ inline float bfval(__bf16 h) {
  return bf2f((unsigned)__builtin_bit_cast(unsigned short, h));
}

__device__ inline bf16x8 load8(const float* __restrict__ p) {
  f32x4 a = *(const f32x4*)p;
  f32x4 b = *(const f32x4*)(p + 4);
  bf16x8 o;
  o[0] = f2bf(a[0]); o[1] = f2bf(a[1]); o[2] = f2bf(a[2]); o[3] = f2bf(a[3]);
  o[4] = f2bf(b[0]); o[5] = f2bf(b[1]); o[6] = f2bf(b[2]); o[7] = f2bf(b[3]);
  return o;
}

#define MFMA16(a, b, c) __builtin_amdgcn_mfma_f32_16x16x32_bf16((a), (b), (c), 0, 0, 0)

// ---- prep: transpose + convert the 4 weight matrices to bf16 Bt[n][k] ----
__global__ void prep_kernel(const float* __restrict__ We1, const float* __restrict__ We2,
                            const float* __restrict__ Wn1, const float* __restrict__ Wn2,
                            __bf16* __restrict__ We1t, __bf16* __restrict__ We2t,
                            __bf16* __restrict__ Wn1t, __bf16* __restrict__ Wn2t) {
  int i = blockIdx.x * blockDim.x + threadIdx.x;
  if (i < 49152) {                       // We1: [384][128] -> [128][384]
    int n = i / 384, k = i % 384;
    We1t[i] = f2bf(We1[k * 128 + n]);
  } else if (i < 65536) {                // We2: [128][128]
    int j = i - 49152; int n = j / 128, k = j % 128;
    We2t[j] = f2bf(We2[k * 128 + n]);
  } else if (i < 98304) {                // Wn1: [256][128] -> [128][256]
    int j = i - 65536; int n = j / 256, k = j % 256;
    Wn1t[j] = f2bf(Wn1[k * 128 + n]);
  } else if (i < 114688) {               // Wn2: [128][128]
    int j = i - 98304; int n = j / 128, k = j % 128;
    Wn2t[j] = f2bf(Wn2[k * 128 + n]);
  }
}

// ---- convert node_h fp32 -> bf16 (12.8 MB; L2/L3-resident gather target) ----
__global__ void conv_node_kernel(const float* __restrict__ nh,
                                 unsigned short* __restrict__ nhb) {
  int i = blockIdx.x * 256 + threadIdx.x;   // 800000 threads x 8 floats
  if (i >= NN * DD / 8) return;
  const float* p = nh + (size_t)i * 8;
  f32x4 a = *(const f32x4*)p;
  f32x4 b = *(const f32x4*)(p + 4);
  u16x8 o;
  o[0] = f2bfu(a[0]); o[1] = f2bfu(a[1]); o[2] = f2bfu(a[2]); o[3] = f2bfu(a[3]);
  o[4] = f2bfu(b[0]); o[5] = f2bfu(b[1]); o[6] = f2bfu(b[2]); o[7] = f2bfu(b[3]);
  *(u16x8*)(nhb + (size_t)i * 8) = o;
}

// ---- CSR build ----
__global__ void hist_kernel(const int* __restrict__ dst, int* __restrict__ counts) {
  int i = blockIdx.x * 256 + threadIdx.x;
  if (i < NE) atomicAdd(&counts[dst[i]], 1);
}
__global__ void scan1_kernel(const int* __restrict__ counts, int* __restrict__ basearr,
                             int* __restrict__ partials) {
  __shared__ int sd[256];
  int t = threadIdx.x;
  int i = blockIdx.x * 256 + t;
  int v = (i < NN) ? counts[i] : 0;
  sd[t] = v; __syncthreads();
  for (int off = 1; off < 256; off <<= 1) {
    int x = (t >= off) ? sd[t - off] : 0;
    __syncthreads();
    sd[t] += x;
    __syncthreads();
  }
  if (i < NN) basearr[i] = sd[t] - v;
  if (t == 255) partials[blockIdx.x] = sd[255];
}
__global__ void scan2_kernel(const int* __restrict__ partials, int* __restrict__ poff,
                             int nparts) {
  __shared__ int sd[256];
  int t = threadIdx.x;
  int v = (t < nparts) ? partials[t] : 0;
  sd[t] = v; __syncthreads();
  for (int off = 1; off < 256; off <<= 1) {
    int x = (t >= off) ? sd[t - off] : 0;
    __syncthreads();
    sd[t] += x;
    __syncthreads();
  }
  if (t < nparts) poff[t] = sd[t] - v;
}
__global__ void scan3_kernel(int* __restrict__ basearr, const int* __restrict__ poff) {
  int i = blockIdx.x * 256 + threadIdx.x;
  if (i < NN) basearr[i] += poff[blockIdx.x];
}
// scatter also records per-CSR-position src value and dst value, so the edge
// kernel needs no second-level indirection for the node gathers.
__global__ void scatter_kernel(const int* __restrict__ src, const int* __restrict__ dst,
                               const int* __restrict__ basearr, int* __restrict__ cursor,
                               int* __restrict__ eids, int* __restrict__ sidv,
                               int* __restrict__ dstv) {
  int i = blockIdx.x * 256 + threadIdx.x;
  if (i < NE) {
    int d = dst[i];
    int p = basearr[d] + atomicAdd(&cursor[d], 1);
    eids[p] = i;
    sidv[p] = src[i];
    dstv[p] = d;
  }
}

// ---- edge MLP layer-1 + fused segment-sum of relu(h1) into S (fp32) ----
// Processes edges in CSR (dst-sorted) order: tile = 128 consecutive CSR
// positions. After relu(h1) is in LDS, a per-column segmented scan emits
// one coalesced fp32 atomic per (segment, column). The per-edge @We2 GEMM
// is deferred to the node kernel via linearity of segment_sum.
__global__ __launch_bounds__(256) void edge_agg_kernel(
    const unsigned short* __restrict__ nhb, const float* __restrict__ edge_h,
    const int* __restrict__ eids, const int* __restrict__ sidv,
    const int* __restrict__ dstv,
    const __bf16* __restrict__ We1t, const float* __restrict__ be1,
    float* __restrict__ S) {
  __shared__ unsigned short h1[128 * 136];
  __shared__ int dloc[128];
  const int tid = (int)threadIdx.x;
  const int w = tid >> 6;
  const int l = tid & 63;
  const int lm = l & 15;
  const int q = l >> 4;
  const int e0 = (int)blockIdx.x * 128;
  const int row0 = w * 32;

  if (tid < 128) dloc[tid] = dstv[e0 + tid];

  const int p0 = e0 + row0 + lm;
  const int p1 = p0 + 16;
  const unsigned short* gA0[2] = {nhb + (size_t)sidv[p0] * DD, nhb + (size_t)dstv[p0] * DD};
  const unsigned short* gA1[2] = {nhb + (size_t)sidv[p1] * DD, nhb + (size_t)dstv[p1] * DD};
  const float* eh0 = edge_h + (size_t)eids[p0] * DD;
  const float* eh1 = edge_h + (size_t)eids[p1] * DD;

  f32x4 acc[2][8];
#pragma unroll
  for (int nt = 0; nt < 8; ++nt) {
    float b = be1[nt * 16 + lm];
    acc[0][nt] = (f32x4){b, b, b, b};
    acc[1][nt] = (f32x4){b, b, b, b};
  }

  // phase 1a: K-steps 0..7  (src-h, dst-h gathers, bf16 direct)
#pragma unroll
  for (int step = 0; step < 8; ++step) {
    const int region = step >> 2;
    const int col = ((step & 3) * 32) + q * 8;
    bf16x8 a0 = __builtin_bit_cast(bf16x8, *(const u16x8*)(gA0[region] + col));
    bf16x8 a1 = __builtin_bit_cast(bf16x8, *(const u16x8*)(gA1[region] + col));
    const __bf16* bp = We1t + (size_t)lm * 384 + step * 32 + q * 8;
#pragma unroll
    for (int nt = 0; nt < 8; ++nt) {
      bf16x8 bb = *(const bf16x8*)(bp + nt * 16 * 384);
      acc[0][nt] = MFMA16(a0, bb, acc[0][nt]);
      acc[1][nt] = MFMA16(a1, bb, acc[1][nt]);
    }
  }
  // phase 1b: K-steps 8..11 (edge_h rows, fp32 convert inline)
#pragma unroll
  for (int s2 = 0; s2 < 4; ++s2) {
    const int col = s2 * 32 + q * 8;
    bf16x8 a0 = load8(eh0 + col);
    bf16x8 a1 = load8(eh1 + col);
    const __bf16* bp = We1t + (size_t)lm * 384 + (8 + s2) * 32 + q * 8;
#pragma unroll
    for (int nt = 0; nt < 8; ++nt) {
      bf16x8 bb = *(const bf16x8*)(bp + nt * 16 * 384);
      acc[0][nt] = MFMA16(a0, bb, acc[0][nt]);
      acc[1][nt] = MFMA16(a1, bb, acc[1][nt]);
    }
  }

  // relu -> LDS tile (bf16), C-layout -> row-major
#pragma unroll
  for (int t = 0; t < 2; ++t)
#pragma unroll
    for (int nt = 0; nt < 8; ++nt)
#pragma unroll
      for (int r = 0; r < 4; ++r) {
        float v = acc[t][nt][r];
        v = v > 0.f ? v : 0.f;
        int m = row0 + t * 16 + q * 4 + r;
        h1[m * 136 + nt * 16 + lm] = f2bfu(v);
      }
  __syncthreads();

  // segmented column reduction: thread = (column, row-half). dst is sorted,
  // so segment boundaries are wave-uniform -> coalesced atomics.
  {
    const int col = tid & 127;
    const int rbeg = (tid >> 7) * 64;
    const int rend = rbeg + 64;
    float a = 0.f;
    int dcur = dloc[rbeg];
    for (int r = rbeg; r < rend; ++r) {
      int d = dloc[r];
      if (d != dcur) {
        unsafeAtomicAdd(&S[(size_t)dcur * DD + col], a);
        a = 0.f;
        dcur = d;
      }
      a += bf2f((unsigned)h1[r * 136 + col]);
    }
    unsafeAtomicAdd(&S[(size_t)dcur * DD + col], a);
  }
}

// ---- node side: agg_m = S@We2 + cnt*be2 (split-precision), then node MLP ----
__global__ __launch_bounds__(256) void node_kernel2(
    const unsigned short* __restrict__ nhb, const float* __restrict__ S,
    const int* __restrict__ counts,
    const __bf16* __restrict__ We2t, const float* __restrict__ be2,
    const __bf16* __restrict__ Wn1t, const float* __restrict__ bn1,
    const __bf16* __restrict__ Wn2t, const float* __restrict__ bn2,
    float* __restrict__ out) {
  __shared__ unsigned short h1[128 * 136];
  const int tid = (int)threadIdx.x;
  const int w = tid >> 6;
  const int l = tid & 63;
  const int lm = l & 15;
  const int q = l >> 4;
  const int n0 = (int)blockIdx.x * 128;
  const int row0 = w * 32;

  int r0 = n0 + row0 + lm;
  int r1 = r0 + 16;
  int c0 = r0 < NN ? r0 : NN - 1;
  int c1 = r1 < NN ? r1 : NN - 1;
  const float* s0p = S + (size_t)c0 * DD;
  const float* s1p = S + (size_t)c1 * DD;

  f32x4 acc[2][8];

  // ---- stage A: acc = cnt*be2 + S @ We2 (bf16 hi/lo split, K doubled) ----
  {
    float cnt0[4], cnt1[4];
#pragma unroll
    for (int r = 0; r < 4; ++r) {
      int ra = n0 + row0 + q * 4 + r;
      int rb = ra + 16;
      cnt0[r] = (ra < NN) ? (float)counts[ra] : 0.f;
      cnt1[r] = (rb < NN) ? (float)counts[rb] : 0.f;
    }
#pragma unroll
    for (int nt = 0; nt < 8; ++nt) {
      float b = be2[nt * 16 + lm];
#pragma unroll
      for (int r = 0; r < 4; ++r) {
        acc[0][nt][r] = cnt0[r] * b;
        acc[1][nt][r] = cnt1[r] * b;
      }
    }
  }
#pragma unroll
  for (int step = 0; step < 4; ++step) {
    const int col = step * 32 + q * 8;
    f32x4 x0a = *(const f32x4*)(s0p + col);
    f32x4 x0b = *(const f32x4*)(s0p + col + 4);
    f32x4 x1a = *(const f32x4*)(s1p + col);
    f32x4 x1b = *(const f32x4*)(s1p + col + 4);
    bf16x8 h0, l0, h8, l8;
#pragma unroll
    for (int j = 0; j < 4; ++j) {
      float v = x0a[j]; __bf16 hh = f2bf(v);
      h0[j] = hh; l0[j] = f2bf(v - bfval(hh));
      v = x0b[j]; hh = f2bf(v);
      h0[j + 4] = hh; l0[j + 4] = f2bf(v - bfval(hh));
      v = x1a[j]; hh = f2bf(v);
      h8[j] = hh; l8[j] = f2bf(v - bfval(hh));
      v = x1b[j]; hh = f2bf(v);
      h8[j + 4] = hh; l8[j + 4] = f2bf(v - bfval(hh));
    }
    const __bf16* bp = We2t + (size_t)lm * 128 + step * 32 + q * 8;
#pragma unroll
    for (int nt = 0; nt < 8; ++nt) {
      bf16x8 bb = *(const bf16x8*)(bp + nt * 16 * 128);
      acc[0][nt] = MFMA16(h0, bb, acc[0][nt]);
      acc[0][nt] = MFMA16(l0, bb, acc[0][nt]);
      acc[1][nt] = MFMA16(h8, bb, acc[1][nt]);
      acc[1][nt] = MFMA16(l8, bb, acc[1][nt]);
    }
  }

  // agg_m tile -> LDS (bf16, A-layout transform)
#pragma unroll
  for (int t = 0; t < 2; ++t)
#pragma unroll
    for (int nt = 0; nt < 8; ++nt)
#pragma unroll
      for (int r = 0; r < 4; ++r) {
        int m = row0 + t * 16 + q * 4 + r;
        h1[m * 136 + nt * 16 + lm] = f2bfu(acc[t][nt][r]);
      }
  __syncthreads();

  // ---- stage B: relu(concat(agg_m, node_h) @ Wn1 + bn1), K = 256 ----
#pragma unroll
  for (int nt = 0; nt < 8; ++nt) {
    float b = bn1[nt * 16 + lm];
    acc[0][nt] = (f32x4){b, b, b, b};
    acc[1][nt] = (f32x4){b, b, b, b};
  }
#pragma unroll
  for (int step = 0; step < 8; ++step) {
    bf16x8 a0, a1;
    if (step < 4) {
      a0 = __builtin_bit_cast(bf16x8, *(const u16x8*)&h1[(row0 + lm) * 136 + step * 32 + q * 8]);
      a1 = __builtin_bit_cast(bf16x8, *(const u16x8*)&h1[(row0 + 16 + lm) * 136 + step * 32 + q * 8]);
    } else {
      const int col = (step - 4) * 32 + q * 8;
      a0 = __builtin_bit_cast(bf16x8, *(const u16x8*)(nhb + (size_t)c0 * DD + col));
      a1 = __builtin_bit_cast(bf16x8, *(const u16x8*)(nhb + (size_t)c1 * DD + col));
    }
    const __bf16* bp = Wn1t + (size_t)lm * 256 + step * 32 + q * 8;
#pragma unroll
    for (int nt = 0; nt < 8; ++nt) {
      bf16x8 bb = *(const bf16x8*)(bp + nt * 16 * 256);
      acc[0][nt] = MFMA16(a0, bb, acc[0][nt]);
      acc[1][nt] = MFMA16(a1, bb, acc[1][nt]);
    }
  }
  __syncthreads();   // all h1 (agg) reads complete before overwrite

#pragma unroll
  for (int t = 0; t < 2; ++t)
#pragma unroll
    for (int nt = 0; nt < 8; ++nt)
#pragma unroll
      for (int r = 0; r < 4; ++r) {
        float v = acc[t][nt][r];
        v = v > 0.f ? v : 0.f;
        int m = row0 + t * 16 + q * 4 + r;
        h1[m * 136 + nt * 16 + lm] = f2bfu(v);
      }
  __syncthreads();

  // ---- stage C: h1 @ Wn2 + bn2, K = 128 ----
#pragma unroll
  for (int nt = 0; nt < 8; ++nt) {
    float b = bn2[nt * 16 + lm];
    acc[0][nt] = (f32x4){b, b, b, b};
    acc[1][nt] = (f32x4){b, b, b, b};
  }
#pragma unroll
  for (int step = 0; step < 4; ++step) {
    bf16x8 a0 = __builtin_bit_cast(bf16x8, *(const u16x8*)&h1[(row0 + lm) * 136 + step * 32 + q * 8]);
    bf16x8 a1 = __builtin_bit_cast(bf16x8, *(const u16x8*)&h1[(row0 + 16 + lm) * 136 + step * 32 + q * 8]);
    const __bf16* bp = Wn2t + (size_t)lm * 128 + step * 32 + q * 8;
#pragma unroll
    for (int nt = 0; nt < 8; ++nt) {
      bf16x8 bb = *(const bf16x8*)(bp + nt * 16 * 128);
      acc[0][nt] = MFMA16(a0, bb, acc[0][nt]);
      acc[1][nt] = MFMA16(a1, bb, acc[1][nt]);
    }
  }

#pragma unroll
  for (int t = 0; t < 2; ++t) {
#pragma unroll
    for (int r = 0; r < 4; ++r) {
      int node = n0 + row0 + t * 16 + q * 4 + r;
      if (node < NN) {
        float* orow = out + (size_t)node * DD + lm;
#pragma unroll
        for (int nt = 0; nt < 8; ++nt)
          orow[nt * 16] = acc[t][nt][r];
      }
    }
  }
}

// ======================= fallback (R1 atomic path) =======================
__global__ __launch_bounds__(256) void edge_fb_kernel(
    const float* __restrict__ node_h, const float* __restrict__ edge_h,
    const int* __restrict__ src, const int* __restrict__ dst,
    const __bf16* __restrict__ We1t, const float* __restrict__ be1,
    const __bf16* __restrict__ We2t, const float* __restrict__ be2,
    float* __restrict__ agg) {
  __shared__ unsigned short h1[128 * 136];
  const int tid = (int)threadIdx.x;
  const int w = tid >> 6;
  const int l = tid & 63;
  const int lm = l & 15;
  const int q = l >> 4;
  const int e0 = (int)blockIdx.x * 128;
  const int row0 = w * 32;

  const int eA0 = e0 + row0 + lm;
  const int eA1 = eA0 + 16;
  const float* srcA0[3];
  const float* srcA1[3];
  srcA0[0] = node_h + (size_t)src[eA0] * DD;
  srcA0[1] = node_h + (size_t)dst[eA0] * DD;
  srcA0[2] = edge_h + (size_t)eA0 * DD;
  srcA1[0] = node_h + (size_t)src[eA1] * DD;
  srcA1[1] = node_h + (size_t)dst[eA1] * DD;
  srcA1[2] = edge_h + (size_t)eA1 * DD;

  f32x4 acc[2][8];
#pragma unroll
  for (int nt = 0; nt < 8; ++nt) {
    float b = be1[nt * 16 + lm];
    acc[0][nt] = (f32x4){b, b, b, b};
    acc[1][nt] = (f32x4){b, b, b, b};
  }
#pragma unroll
  for (int step = 0; step < 12; ++step) {
    const int region = step >> 2;
    const int col = ((step & 3) * 32) + q * 8;
    bf16x8 a0 = load8(srcA0[region] + col);
    bf16x8 a1 = load8(srcA1[region] + col);
    const __bf16* bp = We1t + (size_t)lm * 384 + step * 32 + q * 8;
#pragma unroll
    for (int nt = 0; nt < 8; ++nt) {
      bf16x8 bb = *(const bf16x8*)(bp + nt * 16 * 384);
      acc[0][nt] = MFMA16(a0, bb, acc[0][nt]);
      acc[1][nt] = MFMA16(a1, bb, acc[1][nt]);
    }
  }
#pragma unroll
  for (int t = 0; t < 2; ++t)
#pragma unroll
    for (int nt = 0; nt < 8; ++nt)
#pragma unroll
      for (int r = 0; r < 4; ++r) {
        float v = acc[t][nt][r];
        v = v > 0.f ? v : 0.f;
        int m = row0 + t * 16 + q * 4 + r;
        h1[m * 136 + nt * 16 + lm] = f2bfu(v);
      }
  __syncthreads();
#pragma unroll
  for (int nt = 0; nt < 8; ++nt) {
    float b = be2[nt * 16 + lm];
    acc[0][nt] = (f32x4){b, b, b, b};
    acc[1][nt] = (f32x4){b, b, b, b};
  }
#pragma unroll
  for (int step = 0; step < 4; ++step) {
    bf16x8 a0 = __builtin_bit_cast(bf16x8, *(const u16x8*)&h1[(row0 + lm) * 136 + step * 32 + q * 8]);
    bf16x8 a1 = __builtin_bit_cast(bf16x8, *(const u16x8*)&h1[(row0 + 16 + lm) * 136 + step * 32 + q * 8]);
    const __bf16* bp = We2t + (size_t)lm * 128 + step * 32 + q * 8;
#pragma unroll
    for (int nt = 0; nt < 8; ++nt) {
      bf16x8 bb = *(const bf16x8*)(bp + nt * 16 * 128);
      acc[0][nt] = MFMA16(a0, bb, acc[0][nt]);
      acc[1][nt] = MFMA16(a1, bb, acc[1][nt]);
    }
  }
#pragma unroll
  for (int t = 0; t < 2; ++t) {
#pragma unroll
    for (int r = 0; r < 4; ++r) {
      int e = e0 + row0 + t * 16 + q * 4 + r;
      float* arow = agg + (size_t)dst[e] * DD + lm;
#pragma unroll
      for (int nt = 0; nt < 8; ++nt)
        unsafeAtomicAdd(arow + nt * 16, acc[t][nt][r]);
    }
  }
}

__global__ __launch_bounds__(256) void node_fb_kernel(
    const float* __restrict__ node_h, const float* __restrict__ agg,
    const __bf16* __restrict__ Wn1t, const float* __restrict__ bn1,
    const __bf16* __restrict__ Wn2t, const float* __restrict__ bn2,
    float* __restrict__ out) {
  __shared__ unsigned short h1[128 * 136];
  const int tid = (int)threadIdx.x;
  const int w = tid >> 6;
  const int l = tid & 63;
  const int lm = l & 15;
  const int q = l >> 4;
  const int n0 = (int)blockIdx.x * 128;
  const int row0 = w * 32;

  int r0 = n0 + row0 + lm;
  int r1 = r0 + 16;
  int c0 = r0 < NN ? r0 : NN - 1;
  int c1 = r1 < NN ? r1 : NN - 1;
  const float* srcA0[2] = {agg + (size_t)c0 * DD, node_h + (size_t)c0 * DD};
  const float* srcA1[2] = {agg + (size_t)c1 * DD, node_h + (size_t)c1 * DD};

  f32x4 acc[2][8];
#pragma unroll
  for (int nt = 0; nt < 8; ++nt) {
    float b = bn1[nt * 16 + lm];
    acc[0][nt] = (f32x4){b, b, b, b};
    acc[1][nt] = (f32x4){b, b, b, b};
  }
#pragma unroll
  for (int step = 0; step < 8; ++step) {
    const int region = step >> 2;
    const int col = ((step & 3) * 32) + q * 8;
    bf16x8 a0 = load8(srcA0[region] + col);
    bf16x8 a1 = load8(srcA1[region] + col);
    const __bf16* bp = Wn1t + (size_t)lm * 256 + step * 32 + q * 8;
#pragma unroll
    for (int nt = 0; nt < 8; ++nt) {
      bf16x8 bb = *(const bf16x8*)(bp + nt * 16 * 256);
      acc[0][nt] = MFMA16(a0, bb, acc[0][nt]);
      acc[1][nt] = MFMA16(a1, bb, acc[1][nt]);
    }
  }
#pragma unroll
  for (int t = 0; t < 2; ++t)
#pragma unroll
    for (int nt = 0; nt < 8; ++nt)
#pragma unroll
      for (int r = 0; r < 4; ++r) {
        float v = acc[t][nt][r];
        v = v > 0.f ? v : 0.f;
        int m = row0 + t * 16 + q * 4 + r;
        h1[m * 136 + nt * 16 + lm] = f2bfu(v);
      }
  __syncthreads();
#pragma unroll
  for (int nt = 0; nt < 8; ++nt) {
    float b = bn2[nt * 16 + lm];
    acc[0][nt] = (f32x4){b, b, b, b};
    acc[1][nt] = (f32x4){b, b, b, b};
  }
#pragma unroll
  for (int step = 0; step < 4; ++step) {
    bf16x8 a0 = __builtin_bit_cast(bf16x8, *(const u16x8*)&h1[(row0 + lm) * 136 + step * 32 + q * 8]);
    bf16x8 a1 = __builtin_bit_cast(bf16x8, *(const u16x8*)&h1[(row0 + 16 + lm) * 136 + step * 32 + q * 8]);
    const __bf16* bp = Wn2t + (size_t)lm * 128 + step * 32 + q * 8;
#pragma unroll
    for (int nt = 0; nt < 8; ++nt) {
      bf16x8 bb = *(const bf16x8*)(bp + nt * 16 * 128);
      acc[0][nt] = MFMA16(a0, bb, acc[0][nt]);
      acc[1][nt] = MFMA16(a1, bb, acc[1][nt]);
    }
  }
#pragma unroll
  for (int t = 0; t < 2; ++t) {
#pragma unroll
    for (int r = 0; r < 4; ++r) {
      int node = n0 + row0 + t * 16 + q * 4 + r;
      if (node < NN) {
        float* orow = out + (size_t)node * DD + lm;
#pragma unroll
        for (int nt = 0; nt < 8; ++nt)
          orow[nt * 16] = acc[t][nt][r];
      }
    }
  }
}

extern "C" void kernel_launch(void* const* d_in, const int* in_sizes, int n_in,
                              void* d_out, int out_size, void* d_ws, size_t ws_size,
                              hipStream_t stream) {
  const float* node_h = (const float*)d_in[0];
  const float* edge_h = (const float*)d_in[1];
  const int* src = (const int*)d_in[2];
  const int* dst = (const int*)d_in[3];
  const float* We1 = (const float*)d_in[4];
  const float* be1 = (const float*)d_in[5];
  const float* We2 = (const float*)d_in[6];
  const float* be2 = (const float*)d_in[7];
  const float* Wn1 = (const float*)d_in[8];
  const float* bn1 = (const float*)d_in[9];
  const float* Wn2 = (const float*)d_in[10];
  const float* bn2 = (const float*)d_in[11];

  // CSR-path ws layout (bytes)
  const size_t o_S    = 0;                    //  25,600,000  (fp32 segment sums)
  const size_t o_nhb  = 25600000;             //  12,800,000
  const size_t o_we1  = 38400000;             //      98,304
  const size_t o_we2  = 38498304;             //      32,768
  const size_t o_wn1  = 38531072;             //      65,536
  const size_t o_wn2  = 38596608;             //      32,768
  const size_t o_cnt  = 38629376;             //     200,000
  const size_t o_base = 38829376;             //     200,000
  const size_t o_cur  = 39029376;             //     200,000
  const size_t o_poff = 39229376;             //       1,024
  const size_t o_eids = 39230400;             //   2,560,000
  const size_t o_sidv = 41790400;             //   2,560,000
  const size_t o_dstv = 44350400;             //   2,560,000
  const size_t csr_need = 46910400;

  char* ws = (char*)d_ws;

  if (ws_size >= csr_need) {
    float* S = (float*)(ws + o_S);
    unsigned short* nhb = (unsigned short*)(ws + o_nhb);
    __bf16* We1t = (__bf16*)(ws + o_we1);
    __bf16* We2t = (__bf16*)(ws + o_we2);
    __bf16* Wn1t = (__bf16*)(ws + o_wn1);
    __bf16* Wn2t = (__bf16*)(ws + o_wn2);
    int* counts  = (int*)(ws + o_cnt);
    int* basearr = (int*)(ws + o_base);
    int* cursor  = (int*)(ws + o_cur);
    int* poff    = (int*)(ws + o_poff);
    int* eids    = (int*)(ws + o_eids);
    int* sidv    = (int*)(ws + o_sidv);
    int* dstv    = (int*)(ws + o_dstv);

    hipMemsetAsync(S, 0, (size_t)NN * DD * sizeof(float), stream);
    hipMemsetAsync(counts, 0, NN * sizeof(int), stream);
    hipMemsetAsync(cursor, 0, NN * sizeof(int), stream);
    conv_node_kernel<<<(NN * DD / 8 + 255) / 256, 256, 0, stream>>>(node_h, nhb);
    prep_kernel<<<(114688 + 255) / 256, 256, 0, stream>>>(We1, We2, Wn1, Wn2,
                                                          We1t, We2t, Wn1t, Wn2t);
    hist_kernel<<<(NE + 255) / 256, 256, 0, stream>>>(dst, counts);
    const int nparts = (NN + 255) / 256;   // 196
    // scan1 stores per-block partials in 'cursor' (re-zeroed before scatter)
    scan1_kernel<<<nparts, 256, 0, stream>>>(counts, basearr, cursor);
    scan2_kernel<<<1, 256, 0, stream>>>(cursor, poff, nparts);
    scan3_kernel<<<nparts, 256, 0, stream>>>(basearr, poff);
    hipMemsetAsync(cursor, 0, NN * sizeof(int), stream);
    scatter_kernel<<<(NE + 255) / 256, 256, 0, stream>>>(src, dst, basearr, cursor,
                                                         eids, sidv, dstv);
    edge_agg_kernel<<<NE / 128, 256, 0, stream>>>(nhb, edge_h, eids, sidv, dstv,
                                                  We1t, be1, S);
    node_kernel2<<<(NN + 127) / 128, 256, 0, stream>>>(nhb, S, counts,
                                                       We2t, be2, Wn1t, bn1,
                                                       Wn2t, bn2, (float*)d_out);
  } else {
    // fallback: R1 atomic path (ws >= ~25.9 MB)
    const size_t agg_bytes = (size_t)NN * DD * sizeof(float);
    float* agg = (float*)d_ws;
    char* wbase = ws + agg_bytes;
    __bf16* We1t = (__bf16*)(wbase);
    __bf16* We2t = (__bf16*)(wbase + 98304);
    __bf16* Wn1t = (__bf16*)(wbase + 98304 + 32768);
    __bf16* Wn2t = (__bf16*)(wbase + 98304 + 32768 + 65536);

    hipMemsetAsync(agg, 0, agg_bytes, stream);
    prep_kernel<<<(114688 + 255) / 256, 256, 0, stream>>>(We1, We2, Wn1, Wn2,
                                                          We1t, We2t, Wn1t, Wn2t);
    edge_fb_kernel<<<NE / 128, 256, 0, stream>>>(node_h, edge_h, src, dst,
                                                 We1t, be1, We2t, be2, agg);
    node_fb_kernel<<<(NN + 127) / 128, 256, 0, stream>>>(node_h, agg, Wn1t, bn1,
                                                         Wn2t, bn2, (float*)d_out);
  }
}

// Round 2
// 841.609 us; speedup vs baseline: 1.1731x; 1.0667x over previous
//
#include <hip/hip_runtime.h>

#define NN 50000
#define NE 640000
#define DD 128

typedef float f32x4 __attribute__((ext_vector_type(4)));
typedef __bf16 bf16x8 __attribute__((ext_vector_type(8)));
typedef unsigned short u16x8 __attribute__((ext_vector_type(8)));

__device__ inline __bf16 f2bf(float f) {
  unsigned u = __builtin_bit_cast(unsigned, f);
  u = (u + 0x7fffu + ((u >> 16) & 1u)) >> 16;
  unsigned short h = (unsigned short)u;
  return __builtin_bit_cast(__bf16, h);
}
__device__ inline unsigned short f2bfu(float f) {
  return __builtin_bit_cast(unsigned short, f2bf(f));
}
__device__ inline float bf2f(unsigned bits16) {
  return __builtin_bit_cast(float, bits16 << 16);
}
__device__ inline float bfval(__bf16 h) {
  return bf2f((unsigned)__builtin_bit_cast(unsigned short, h));
}

__device__ inline bf16x8 load8(const float* __restrict__ p) {
  f32x4 a = *(const f32x4*)p;
  f32x4 b = *(const f32x4*)(p + 4);
  bf16x8 o;
  o[0] = f2bf(a[0]); o[1] = f2bf(a[1]); o[2] = f2bf(a[2]); o[3] = f2bf(a[3]);
  o[4] = f2bf(b[0]); o[5] = f2bf(b[1]); o[6] = f2bf(b[2]); o[7] = f2bf(b[3]);
  return o;
}

#define MFMA16(a, b, c) __builtin_amdgcn_mfma_f32_16x16x32_bf16((a), (b), (c), 0, 0, 0)

// ---- prep: transpose + convert the 4 weight matrices to bf16 Bt[n][k] ----
__global__ void prep_kernel(const float* __restrict__ We1, const float* __restrict__ We2,
                            const float* __restrict__ Wn1, const float* __restrict__ Wn2,
                            __bf16* __restrict__ We1t, __bf16* __restrict__ We2t,
                            __bf16* __restrict__ Wn1t, __bf16* __restrict__ Wn2t) {
  int i = blockIdx.x * blockDim.x + threadIdx.x;
  if (i < 49152) {                       // We1: [384][128] -> [128][384]
    int n = i / 384, k = i % 384;
    We1t[i] = f2bf(We1[k * 128 + n]);
  } else if (i < 65536) {                // We2: [128][128]
    int j = i - 49152; int n = j / 128, k = j % 128;
    We2t[j] = f2bf(We2[k * 128 + n]);
  } else if (i < 98304) {                // Wn1: [256][128] -> [128][256]
    int j = i - 65536; int n = j / 256, k = j % 256;
    Wn1t[j] = f2bf(Wn1[k * 128 + n]);
  } else if (i < 114688) {               // Wn2: [128][128]
    int j = i - 98304; int n = j / 128, k = j % 128;
    Wn2t[j] = f2bf(Wn2[k * 128 + n]);
  }
}

// ---- convert node_h fp32 -> bf16 (12.8 MB; L2/L3-resident gather target) ----
__global__ void conv_node_kernel(const float* __restrict__ nh,
                                 unsigned short* __restrict__ nhb) {
  int i = blockIdx.x * 256 + threadIdx.x;
  if (i >= NN * DD / 8) return;
  const float* p = nh + (size_t)i * 8;
  f32x4 a = *(const f32x4*)p;
  f32x4 b = *(const f32x4*)(p + 4);
  u16x8 o;
  o[0] = f2bfu(a[0]); o[1] = f2bfu(a[1]); o[2] = f2bfu(a[2]); o[3] = f2bfu(a[3]);
  o[4] = f2bfu(b[0]); o[5] = f2bfu(b[1]); o[6] = f2bfu(b[2]); o[7] = f2bfu(b[3]);
  *(u16x8*)(nhb + (size_t)i * 8) = o;
}

// ---- D[n] = node_h[n] @ We1[dst block] + be1 (fp32, per-node precompute) ----
__global__ __launch_bounds__(256) void dnode_kernel(
    const unsigned short* __restrict__ nhb, const __bf16* __restrict__ We1t,
    const float* __restrict__ be1, float* __restrict__ Dg) {
  const int tid = (int)threadIdx.x;
  const int w = tid >> 6;
  const int l = tid & 63;
  const int lm = l & 15;
  const int q = l >> 4;
  const int n0 = (int)blockIdx.x * 128;
  const int row0 = w * 32;

  int r0 = n0 + row0 + lm;
  int r1 = r0 + 16;
  int c0 = r0 < NN ? r0 : NN - 1;
  int c1 = r1 < NN ? r1 : NN - 1;

  f32x4 acc[2][8];
#pragma unroll
  for (int nt = 0; nt < 8; ++nt) {
    float b = be1[nt * 16 + lm];
    acc[0][nt] = (f32x4){b, b, b, b};
    acc[1][nt] = (f32x4){b, b, b, b};
  }
#pragma unroll
  for (int s = 0; s < 4; ++s) {
    const int col = s * 32 + q * 8;
    bf16x8 a0 = __builtin_bit_cast(bf16x8, *(const u16x8*)(nhb + (size_t)c0 * DD + col));
    bf16x8 a1 = __builtin_bit_cast(bf16x8, *(const u16x8*)(nhb + (size_t)c1 * DD + col));
    const __bf16* bp = We1t + (size_t)lm * 384 + 128 + s * 32 + q * 8;
#pragma unroll
    for (int nt = 0; nt < 8; ++nt) {
      bf16x8 bb = *(const bf16x8*)(bp + nt * 16 * 384);
      acc[0][nt] = MFMA16(a0, bb, acc[0][nt]);
      acc[1][nt] = MFMA16(a1, bb, acc[1][nt]);
    }
  }
#pragma unroll
  for (int t = 0; t < 2; ++t) {
#pragma unroll
    for (int r = 0; r < 4; ++r) {
      int node = n0 + row0 + t * 16 + q * 4 + r;
      if (node < NN) {
        float* orow = Dg + (size_t)node * DD + lm;
#pragma unroll
        for (int nt = 0; nt < 8; ++nt)
          orow[nt * 16] = acc[t][nt][r];
      }
    }
  }
}

// ---- CSR build ----
__global__ void hist_kernel(const int* __restrict__ dst, int* __restrict__ counts) {
  int i = blockIdx.x * 256 + threadIdx.x;
  if (i < NE) atomicAdd(&counts[dst[i]], 1);
}
__global__ void scan1_kernel(const int* __restrict__ counts, int* __restrict__ basearr,
                             int* __restrict__ partials) {
  __shared__ int sd[256];
  int t = threadIdx.x;
  int i = blockIdx.x * 256 + t;
  int v = (i < NN) ? counts[i] : 0;
  sd[t] = v; __syncthreads();
  for (int off = 1; off < 256; off <<= 1) {
    int x = (t >= off) ? sd[t - off] : 0;
    __syncthreads();
    sd[t] += x;
    __syncthreads();
  }
  if (i < NN) basearr[i] = sd[t] - v;
  if (t == 255) partials[blockIdx.x] = sd[255];
}
__global__ void scan2_kernel(const int* __restrict__ partials, int* __restrict__ poff,
                             int nparts) {
  __shared__ int sd[256];
  int t = threadIdx.x;
  int v = (t < nparts) ? partials[t] : 0;
  sd[t] = v; __syncthreads();
  for (int off = 1; off < 256; off <<= 1) {
    int x = (t >= off) ? sd[t - off] : 0;
    __syncthreads();
    sd[t] += x;
    __syncthreads();
  }
  if (t < nparts) poff[t] = sd[t] - v;
}
// scatter folds the scan3 poff add and records per-CSR-position src/dst.
__global__ void scatter_kernel(const int* __restrict__ src, const int* __restrict__ dst,
                               const int* __restrict__ basearr, const int* __restrict__ poff,
                               int* __restrict__ cursor, int* __restrict__ eids,
                               int* __restrict__ sidv, int* __restrict__ dstv) {
  int i = blockIdx.x * 256 + threadIdx.x;
  if (i < NE) {
    int d = dst[i];
    int p = basearr[d] + poff[d >> 8] + atomicAdd(&cursor[d], 1);
    eids[p] = i;
    sidv[p] = src[i];
    dstv[p] = d;
  }
}

// ---- edge MLP layer-1 (K=256: src + edge blocks; dst block folded via D) ----
// + fused segment-sum of relu into S (fp32). CSR-ordered tiles.
__global__ __launch_bounds__(256) void edge_agg_kernel(
    const unsigned short* __restrict__ nhb, const float* __restrict__ edge_h,
    const int* __restrict__ eids, const int* __restrict__ sidv,
    const int* __restrict__ dstv, const float* __restrict__ Dg,
    const __bf16* __restrict__ We1t, float* __restrict__ S) {
  __shared__ unsigned short h1[128 * 136];     // also overlaid as Dlds (64x129 f32)
  __shared__ int dloc[128];
  __shared__ int sidx[128];
  __shared__ int segdst[128];
  __shared__ int wcnt0s, nsegS;
  float* Dlds = (float*)h1;

  const int tid = (int)threadIdx.x;
  const int w = tid >> 6;
  const int l = tid & 63;
  const int lm = l & 15;
  const int q = l >> 4;
  const int e0 = (int)blockIdx.x * 128;
  const int row0 = w * 32;
  const int p0 = e0 + row0 + lm;
  const int p1 = p0 + 16;

  // gather pointers (2 dependent scalar loads, once per block)
  const unsigned short* sp0 = nhb + (size_t)sidv[p0] * DD;
  const unsigned short* sp1 = nhb + (size_t)sidv[p1] * DD;
  const float* ehp0 = edge_h + (size_t)eids[p0] * DD;
  const float* ehp1 = edge_h + (size_t)eids[p1] * DD;

  // ---- prefetch ALL A operands (16 gather loads in flight per wave) ----
  u16x8 sa0[4], sa1[4];
#pragma unroll
  for (int s = 0; s < 4; ++s) {
    sa0[s] = *(const u16x8*)(sp0 + s * 32 + q * 8);
    sa1[s] = *(const u16x8*)(sp1 + s * 32 + q * 8);
  }
  bf16x8 ea0[4], ea1[4];
#pragma unroll
  for (int s = 0; s < 4; ++s) {
    ea0[s] = load8(ehp0 + s * 32 + q * 8);
    ea1[s] = load8(ehp1 + s * 32 + q * 8);
  }

  // ---- segment-index scan over the 128 tile rows (waves 0,1) ----
  int d = 0, flag = 0, idx = 0;
  if (tid < 128) {
    d = dstv[e0 + tid];
    dloc[tid] = d;
    int dp = (tid == 0) ? -1 : dstv[e0 + tid - 1];
    flag = (d != dp) ? 1 : 0;
    unsigned long long mask = __ballot(flag);
    int lane = tid & 63;
    idx = (int)__popcll(mask & ((1ull << lane) - 1)) + flag - 1;
    if (tid == 63) wcnt0s = (int)__popcll(mask);
  }
  __syncthreads();
  if (tid < 128) {
    if (tid >= 64) idx += wcnt0s;
    sidx[tid] = idx;
    if (flag) segdst[idx] = d;
    if (tid == 127) nsegS = idx + 1;
  }
  __syncthreads();
  const int nsegT = nsegS;

  // ---- cooperative stage of distinct D rows into LDS (overlay on h1) ----
  {
    const int nstage = nsegT < 64 ? nsegT : 64;
    const int total = nstage << 7;
    for (int base = 0; base < total; base += 1024) {
      float v[4];
#pragma unroll
      for (int u = 0; u < 4; ++u) {
        int i = base + u * 256 + tid;
        if (i < total) v[u] = Dg[(size_t)segdst[i >> 7] * DD + (i & 127)];
      }
#pragma unroll
      for (int u = 0; u < 4; ++u) {
        int i = base + u * 256 + tid;
        if (i < total) Dlds[(i >> 7) * 129 + (i & 127)] = v[u];
      }
    }
  }

  // ---- K-loop: 8 steps (4 src-h + 4 edge_h), acc starts at 0 ----
  f32x4 acc[2][8];
#pragma unroll
  for (int nt = 0; nt < 8; ++nt) {
    acc[0][nt] = (f32x4){0.f, 0.f, 0.f, 0.f};
    acc[1][nt] = (f32x4){0.f, 0.f, 0.f, 0.f};
  }
#pragma unroll
  for (int s = 0; s < 4; ++s) {
    bf16x8 a0 = __builtin_bit_cast(bf16x8, sa0[s]);
    bf16x8 a1 = __builtin_bit_cast(bf16x8, sa1[s]);
    const __bf16* bp = We1t + (size_t)lm * 384 + s * 32 + q * 8;
#pragma unroll
    for (int nt = 0; nt < 8; ++nt) {
      bf16x8 bb = *(const bf16x8*)(bp + nt * 16 * 384);
      acc[0][nt] = MFMA16(a0, bb, acc[0][nt]);
      acc[1][nt] = MFMA16(a1, bb, acc[1][nt]);
    }
  }
#pragma unroll
  for (int s = 0; s < 4; ++s) {
    const __bf16* bp = We1t + (size_t)lm * 384 + 256 + s * 32 + q * 8;
#pragma unroll
    for (int nt = 0; nt < 8; ++nt) {
      bf16x8 bb = *(const bf16x8*)(bp + nt * 16 * 384);
      acc[0][nt] = MFMA16(ea0[s], bb, acc[0][nt]);
      acc[1][nt] = MFMA16(ea1[s], bb, acc[1][nt]);
    }
  }
  __syncthreads();   // Dlds stage writes visible to all waves

  // ---- add D (dst contribution + be1), relu -> keep in acc ----
  if (nsegT <= 64) {
#pragma unroll
    for (int t = 0; t < 2; ++t)
#pragma unroll
      for (int r = 0; r < 4; ++r) {
        int row = row0 + t * 16 + q * 4 + r;
        int si = sidx[row];
#pragma unroll
        for (int nt = 0; nt < 8; ++nt) {
          float v = acc[t][nt][r] + Dlds[si * 129 + nt * 16 + lm];
          acc[t][nt][r] = v > 0.f ? v : 0.f;
        }
      }
  } else {   // rare: degenerate tiles with >64 segments read D from global
#pragma unroll
    for (int t = 0; t < 2; ++t)
#pragma unroll
      for (int r = 0; r < 4; ++r) {
        int row = row0 + t * 16 + q * 4 + r;
        const float* drow = Dg + (size_t)dloc[row] * DD + lm;
#pragma unroll
        for (int nt = 0; nt < 8; ++nt) {
          float v = acc[t][nt][r] + drow[nt * 16];
          acc[t][nt][r] = v > 0.f ? v : 0.f;
        }
      }
  }
  __syncthreads();   // Dlds dead; h1 space reusable

  // ---- relu tile -> h1 (bf16, row-major) ----
#pragma unroll
  for (int t = 0; t < 2; ++t)
#pragma unroll
    for (int nt = 0; nt < 8; ++nt)
#pragma unroll
      for (int r = 0; r < 4; ++r) {
        int m = row0 + t * 16 + q * 4 + r;
        h1[m * 136 + nt * 16 + lm] = f2bfu(acc[t][nt][r]);
      }
  __syncthreads();

  // ---- segmented column reduction -> coalesced fp32 atomics into S ----
  {
    const int col = tid & 127;
    const int rbeg = (tid >> 7) * 64;
    const int rend = rbeg + 64;
    float a = 0.f;
    int dcur = dloc[rbeg];
    for (int r = rbeg; r < rend; ++r) {
      int dd = dloc[r];
      if (dd != dcur) {
        unsafeAtomicAdd(&S[(size_t)dcur * DD + col], a);
        a = 0.f;
        dcur = dd;
      }
      a += bf2f((unsigned)h1[r * 136 + col]);
    }
    unsafeAtomicAdd(&S[(size_t)dcur * DD + col], a);
  }
}

// ---- node side: agg_m = S@We2 + cnt*be2 (split-precision), then node MLP ----
__global__ __launch_bounds__(256) void node_kernel2(
    const unsigned short* __restrict__ nhb, const float* __restrict__ S,
    const int* __restrict__ counts,
    const __bf16* __restrict__ We2t, const float* __restrict__ be2,
    const __bf16* __restrict__ Wn1t, const float* __restrict__ bn1,
    const __bf16* __restrict__ Wn2t, const float* __restrict__ bn2,
    float* __restrict__ out) {
  __shared__ unsigned short h1[128 * 136];
  const int tid = (int)threadIdx.x;
  const int w = tid >> 6;
  const int l = tid & 63;
  const int lm = l & 15;
  const int q = l >> 4;
  const int n0 = (int)blockIdx.x * 128;
  const int row0 = w * 32;

  int r0 = n0 + row0 + lm;
  int r1 = r0 + 16;
  int c0 = r0 < NN ? r0 : NN - 1;
  int c1 = r1 < NN ? r1 : NN - 1;
  const float* s0p = S + (size_t)c0 * DD;
  const float* s1p = S + (size_t)c1 * DD;

  f32x4 acc[2][8];

  // ---- stage A: acc = cnt*be2 + S @ We2 (bf16 hi/lo split, K doubled) ----
  {
    float cnt0[4], cnt1[4];
#pragma unroll
    for (int r = 0; r < 4; ++r) {
      int ra = n0 + row0 + q * 4 + r;
      int rb = ra + 16;
      cnt0[r] = (ra < NN) ? (float)counts[ra] : 0.f;
      cnt1[r] = (rb < NN) ? (float)counts[rb] : 0.f;
    }
#pragma unroll
    for (int nt = 0; nt < 8; ++nt) {
      float b = be2[nt * 16 + lm];
#pragma unroll
      for (int r = 0; r < 4; ++r) {
        acc[0][nt][r] = cnt0[r] * b;
        acc[1][nt][r] = cnt1[r] * b;
      }
    }
  }
#pragma unroll
  for (int step = 0; step < 4; ++step) {
    const int col = step * 32 + q * 8;
    f32x4 x0a = *(const f32x4*)(s0p + col);
    f32x4 x0b = *(const f32x4*)(s0p + col + 4);
    f32x4 x1a = *(const f32x4*)(s1p + col);
    f32x4 x1b = *(const f32x4*)(s1p + col + 4);
    bf16x8 h0, l0, h8, l8;
#pragma unroll
    for (int j = 0; j < 4; ++j) {
      float v = x0a[j]; __bf16 hh = f2bf(v);
      h0[j] = hh; l0[j] = f2bf(v - bfval(hh));
      v = x0b[j]; hh = f2bf(v);
      h0[j + 4] = hh; l0[j + 4] = f2bf(v - bfval(hh));
      v = x1a[j]; hh = f2bf(v);
      h8[j] = hh; l8[j] = f2bf(v - bfval(hh));
      v = x1b[j]; hh = f2bf(v);
      h8[j + 4] = hh; l8[j + 4] = f2bf(v - bfval(hh));
    }
    const __bf16* bp = We2t + (size_t)lm * 128 + step * 32 + q * 8;
#pragma unroll
    for (int nt = 0; nt < 8; ++nt) {
      bf16x8 bb = *(const bf16x8*)(bp + nt * 16 * 128);
      acc[0][nt] = MFMA16(h0, bb, acc[0][nt]);
      acc[0][nt] = MFMA16(l0, bb, acc[0][nt]);
      acc[1][nt] = MFMA16(h8, bb, acc[1][nt]);
      acc[1][nt] = MFMA16(l8, bb, acc[1][nt]);
    }
  }

  // agg_m tile -> LDS (bf16, A-layout transform)
#pragma unroll
  for (int t = 0; t < 2; ++t)
#pragma unroll
    for (int nt = 0; nt < 8; ++nt)
#pragma unroll
      for (int r = 0; r < 4; ++r) {
        int m = row0 + t * 16 + q * 4 + r;
        h1[m * 136 + nt * 16 + lm] = f2bfu(acc[t][nt][r]);
      }
  __syncthreads();

  // ---- stage B: relu(concat(agg_m, node_h) @ Wn1 + bn1), K = 256 ----
#pragma unroll
  for (int nt = 0; nt < 8; ++nt) {
    float b = bn1[nt * 16 + lm];
    acc[0][nt] = (f32x4){b, b, b, b};
    acc[1][nt] = (f32x4){b, b, b, b};
  }
#pragma unroll
  for (int step = 0; step < 8; ++step) {
    bf16x8 a0, a1;
    if (step < 4) {
      a0 = __builtin_bit_cast(bf16x8, *(const u16x8*)&h1[(row0 + lm) * 136 + step * 32 + q * 8]);
      a1 = __builtin_bit_cast(bf16x8, *(const u16x8*)&h1[(row0 + 16 + lm) * 136 + step * 32 + q * 8]);
    } else {
      const int col = (step - 4) * 32 + q * 8;
      a0 = __builtin_bit_cast(bf16x8, *(const u16x8*)(nhb + (size_t)c0 * DD + col));
      a1 = __builtin_bit_cast(bf16x8, *(const u16x8*)(nhb + (size_t)c1 * DD + col));
    }
    const __bf16* bp = Wn1t + (size_t)lm * 256 + step * 32 + q * 8;
#pragma unroll
    for (int nt = 0; nt < 8; ++nt) {
      bf16x8 bb = *(const bf16x8*)(bp + nt * 16 * 256);
      acc[0][nt] = MFMA16(a0, bb, acc[0][nt]);
      acc[1][nt] = MFMA16(a1, bb, acc[1][nt]);
    }
  }
  __syncthreads();   // all h1 (agg) reads complete before overwrite

#pragma unroll
  for (int t = 0; t < 2; ++t)
#pragma unroll
    for (int nt = 0; nt < 8; ++nt)
#pragma unroll
      for (int r = 0; r < 4; ++r) {
        float v = acc[t][nt][r];
        v = v > 0.f ? v : 0.f;
        int m = row0 + t * 16 + q * 4 + r;
        h1[m * 136 + nt * 16 + lm] = f2bfu(v);
      }
  __syncthreads();

  // ---- stage C: h1 @ Wn2 + bn2, K = 128 ----
#pragma unroll
  for (int nt = 0; nt < 8; ++nt) {
    float b = bn2[nt * 16 + lm];
    acc[0][nt] = (f32x4){b, b, b, b};
    acc[1][nt] = (f32x4){b, b, b, b};
  }
#pragma unroll
  for (int step = 0; step < 4; ++step) {
    bf16x8 a0 = __builtin_bit_cast(bf16x8, *(const u16x8*)&h1[(row0 + lm) * 136 + step * 32 + q * 8]);
    bf16x8 a1 = __builtin_bit_cast(bf16x8, *(const u16x8*)&h1[(row0 + 16 + lm) * 136 + step * 32 + q * 8]);
    const __bf16* bp = Wn2t + (size_t)lm * 128 + step * 32 + q * 8;
#pragma unroll
    for (int nt = 0; nt < 8; ++nt) {
      bf16x8 bb = *(const bf16x8*)(bp + nt * 16 * 128);
      acc[0][nt] = MFMA16(a0, bb, acc[0][nt]);
      acc[1][nt] = MFMA16(a1, bb, acc[1][nt]);
    }
  }

#pragma unroll
  for (int t = 0; t < 2; ++t) {
#pragma unroll
    for (int r = 0; r < 4; ++r) {
      int node = n0 + row0 + t * 16 + q * 4 + r;
      if (node < NN) {
        float* orow = out + (size_t)node * DD + lm;
#pragma unroll
        for (int nt = 0; nt < 8; ++nt)
          orow[nt * 16] = acc[t][nt][r];
      }
    }
  }
}

// ======================= fallback (R1 atomic path) =======================
__global__ __launch_bounds__(256) void edge_fb_kernel(
    const float* __restrict__ node_h, const float* __restrict__ edge_h,
    const int* __restrict__ src, const int* __restrict__ dst,
    const __bf16* __restrict__ We1t, const float* __restrict__ be1,
    const __bf16* __restrict__ We2t, const float* __restrict__ be2,
    float* __restrict__ agg) {
  __shared__ unsigned short h1[128 * 136];
  const int tid = (int)threadIdx.x;
  const int w = tid >> 6;
  const int l = tid & 63;
  const int lm = l & 15;
  const int q = l >> 4;
  const int e0 = (int)blockIdx.x * 128;
  const int row0 = w * 32;

  const int eA0 = e0 + row0 + lm;
  const int eA1 = eA0 + 16;
  const float* srcA0[3];
  const float* srcA1[3];
  srcA0[0] = node_h + (size_t)src[eA0] * DD;
  srcA0[1] = node_h + (size_t)dst[eA0] * DD;
  srcA0[2] = edge_h + (size_t)eA0 * DD;
  srcA1[0] = node_h + (size_t)src[eA1] * DD;
  srcA1[1] = node_h + (size_t)dst[eA1] * DD;
  srcA1[2] = edge_h + (size_t)eA1 * DD;

  f32x4 acc[2][8];
#pragma unroll
  for (int nt = 0; nt < 8; ++nt) {
    float b = be1[nt * 16 + lm];
    acc[0][nt] = (f32x4){b, b, b, b};
    acc[1][nt] = (f32x4){b, b, b, b};
  }
#pragma unroll
  for (int step = 0; step < 12; ++step) {
    const int region = step >> 2;
    const int col = ((step & 3) * 32) + q * 8;
    bf16x8 a0 = load8(srcA0[region] + col);
    bf16x8 a1 = load8(srcA1[region] + col);
    const __bf16* bp = We1t + (size_t)lm * 384 + step * 32 + q * 8;
#pragma unroll
    for (int nt = 0; nt < 8; ++nt) {
      bf16x8 bb = *(const bf16x8*)(bp + nt * 16 * 384);
      acc[0][nt] = MFMA16(a0, bb, acc[0][nt]);
      acc[1][nt] = MFMA16(a1, bb, acc[1][nt]);
    }
  }
#pragma unroll
  for (int t = 0; t < 2; ++t)
#pragma unroll
    for (int nt = 0; nt < 8; ++nt)
#pragma unroll
      for (int r = 0; r < 4; ++r) {
        float v = acc[t][nt][r];
        v = v > 0.f ? v : 0.f;
        int m = row0 + t * 16 + q * 4 + r;
        h1[m * 136 + nt * 16 + lm] = f2bfu(v);
      }
  __syncthreads();
#pragma unroll
  for (int nt = 0; nt < 8; ++nt) {
    float b = be2[nt * 16 + lm];
    acc[0][nt] = (f32x4){b, b, b, b};
    acc[1][nt] = (f32x4){b, b, b, b};
  }
#pragma unroll
  for (int step = 0; step < 4; ++step) {
    bf16x8 a0 = __builtin_bit_cast(bf16x8, *(const u16x8*)&h1[(row0 + lm) * 136 + step * 32 + q * 8]);
    bf16x8 a1 = __builtin_bit_cast(bf16x8, *(const u16x8*)&h1[(row0 + 16 + lm) * 136 + step * 32 + q * 8]);
    const __bf16* bp = We2t + (size_t)lm * 128 + step * 32 + q * 8;
#pragma unroll
    for (int nt = 0; nt < 8; ++nt) {
      bf16x8 bb = *(const bf16x8*)(bp + nt * 16 * 128);
      acc[0][nt] = MFMA16(a0, bb, acc[0][nt]);
      acc[1][nt] = MFMA16(a1, bb, acc[1][nt]);
    }
  }
#pragma unroll
  for (int t = 0; t < 2; ++t) {
#pragma unroll
    for (int r = 0; r < 4; ++r) {
      int e = e0 + row0 + t * 16 + q * 4 + r;
      float* arow = agg + (size_t)dst[e] * DD + lm;
#pragma unroll
      for (int nt = 0; nt < 8; ++nt)
        unsafeAtomicAdd(arow + nt * 16, acc[t][nt][r]);
    }
  }
}

__global__ __launch_bounds__(256) void node_fb_kernel(
    const float* __restrict__ node_h, const float* __restrict__ agg,
    const __bf16* __restrict__ Wn1t, const float* __restrict__ bn1,
    const __bf16* __restrict__ Wn2t, const float* __restrict__ bn2,
    float* __restrict__ out) {
  __shared__ unsigned short h1[128 * 136];
  const int tid = (int)threadIdx.x;
  const int w = tid >> 6;
  const int l = tid & 63;
  const int lm = l & 15;
  const int q = l >> 4;
  const int n0 = (int)blockIdx.x * 128;
  const int row0 = w * 32;

  int r0 = n0 + row0 + lm;
  int r1 = r0 + 16;
  int c0 = r0 < NN ? r0 : NN - 1;
  int c1 = r1 < NN ? r1 : NN - 1;
  const float* srcA0[2] = {agg + (size_t)c0 * DD, node_h + (size_t)c0 * DD};
  const float* srcA1[2] = {agg + (size_t)c1 * DD, node_h + (size_t)c1 * DD};

  f32x4 acc[2][8];
#pragma unroll
  for (int nt = 0; nt < 8; ++nt) {
    float b = bn1[nt * 16 + lm];
    acc[0][nt] = (f32x4){b, b, b, b};
    acc[1][nt] = (f32x4){b, b, b, b};
  }
#pragma unroll
  for (int step = 0; step < 8; ++step) {
    const int region = step >> 2;
    const int col = ((step & 3) * 32) + q * 8;
    bf16x8 a0 = load8(srcA0[region] + col);
    bf16x8 a1 = load8(srcA1[region] + col);
    const __bf16* bp = Wn1t + (size_t)lm * 256 + step * 32 + q * 8;
#pragma unroll
    for (int nt = 0; nt < 8; ++nt) {
      bf16x8 bb = *(const bf16x8*)(bp + nt * 16 * 256);
      acc[0][nt] = MFMA16(a0, bb, acc[0][nt]);
      acc[1][nt] = MFMA16(a1, bb, acc[1][nt]);
    }
  }
#pragma unroll
  for (int t = 0; t < 2; ++t)
#pragma unroll
    for (int nt = 0; nt < 8; ++nt)
#pragma unroll
      for (int r = 0; r < 4; ++r) {
        float v = acc[t][nt][r];
        v = v > 0.f ? v : 0.f;
        int m = row0 + t * 16 + q * 4 + r;
        h1[m * 136 + nt * 16 + lm] = f2bfu(v);
      }
  __syncthreads();
#pragma unroll
  for (int nt = 0; nt < 8; ++nt) {
    float b = bn2[nt * 16 + lm];
    acc[0][nt] = (f32x4){b, b, b, b};
    acc[1][nt] = (f32x4){b, b, b, b};
  }
#pragma unroll
  for (int step = 0; step < 4; ++step) {
    bf16x8 a0 = __builtin_bit_cast(bf16x8, *(const u16x8*)&h1[(row0 + lm) * 136 + step * 32 + q * 8]);
    bf16x8 a1 = __builtin_bit_cast(bf16x8, *(const u16x8*)&h1[(row0 + 16 + lm) * 136 + step * 32 + q * 8]);
    const __bf16* bp = Wn2t + (size_t)lm * 128 + step * 32 + q * 8;
#pragma unroll
    for (int nt = 0; nt < 8; ++nt) {
      bf16x8 bb = *(const bf16x8*)(bp + nt * 16 * 128);
      acc[0][nt] = MFMA16(a0, bb, acc[0][nt]);
      acc[1][nt] = MFMA16(a1, bb, acc[1][nt]);
    }
  }
#pragma unroll
  for (int t = 0; t < 2; ++t) {
#pragma unroll
    for (int r = 0; r < 4; ++r) {
      int node = n0 + row0 + t * 16 + q * 4 + r;
      if (node < NN) {
        float* orow = out + (size_t)node * DD + lm;
#pragma unroll
        for (int nt = 0; nt < 8; ++nt)
          orow[nt * 16] = acc[t][nt][r];
      }
    }
  }
}

extern "C" void kernel_launch(void* const* d_in, const int* in_sizes, int n_in,
                              void* d_out, int out_size, void* d_ws, size_t ws_size,
                              hipStream_t stream) {
  const float* node_h = (const float*)d_in[0];
  const float* edge_h = (const float*)d_in[1];
  const int* src = (const int*)d_in[2];
  const int* dst = (const int*)d_in[3];
  const float* We1 = (const float*)d_in[4];
  const float* be1 = (const float*)d_in[5];
  const float* We2 = (const float*)d_in[6];
  const float* be2 = (const float*)d_in[7];
  const float* Wn1 = (const float*)d_in[8];
  const float* bn1 = (const float*)d_in[9];
  const float* Wn2 = (const float*)d_in[10];
  const float* bn2 = (const float*)d_in[11];

  // CSR-path ws layout (bytes)
  const size_t o_S    = 0;                    //  25,600,000  fp32 segment sums
  const size_t o_D    = 25600000;             //  25,600,000  fp32 dst-precompute
  const size_t o_nhb  = 51200000;             //  12,800,000
  const size_t o_we1  = 64000000;             //      98,304
  const size_t o_we2  = 64098304;             //      32,768
  const size_t o_wn1  = 64131072;             //      65,536
  const size_t o_wn2  = 64196608;             //      32,768
  const size_t o_cnt  = 64229376;             //     200,000
  const size_t o_base = 64429376;             //     200,000
  const size_t o_cur  = 64629376;             //     200,000
  const size_t o_poff = 64829376;             //       1,024
  const size_t o_eids = 64830400;             //   2,560,000
  const size_t o_sidv = 67390400;             //   2,560,000
  const size_t o_dstv = 69950400;             //   2,560,000
  const size_t csr_need = 72510400;

  char* ws = (char*)d_ws;

  if (ws_size >= csr_need) {
    float* S     = (float*)(ws + o_S);
    float* Dg    = (float*)(ws + o_D);
    unsigned short* nhb = (unsigned short*)(ws + o_nhb);
    __bf16* We1t = (__bf16*)(ws + o_we1);
    __bf16* We2t = (__bf16*)(ws + o_we2);
    __bf16* Wn1t = (__bf16*)(ws + o_wn1);
    __bf16* Wn2t = (__bf16*)(ws + o_wn2);
    int* counts  = (int*)(ws + o_cnt);
    int* basearr = (int*)(ws + o_base);
    int* cursor  = (int*)(ws + o_cur);
    int* poff    = (int*)(ws + o_poff);
    int* eids    = (int*)(ws + o_eids);
    int* sidv    = (int*)(ws + o_sidv);
    int* dstv    = (int*)(ws + o_dstv);

    hipMemsetAsync(S, 0, (size_t)NN * DD * sizeof(float), stream);
    hipMemsetAsync(counts, 0, NN * sizeof(int), stream);
    hipMemsetAsync(cursor, 0, NN * sizeof(int), stream);
    conv_node_kernel<<<(NN * DD / 8 + 255) / 256, 256, 0, stream>>>(node_h, nhb);
    prep_kernel<<<(114688 + 255) / 256, 256, 0, stream>>>(We1, We2, Wn1, Wn2,
                                                          We1t, We2t, Wn1t, Wn2t);
    dnode_kernel<<<(NN + 127) / 128, 256, 0, stream>>>(nhb, We1t, be1, Dg);
    hist_kernel<<<(NE + 255) / 256, 256, 0, stream>>>(dst, counts);
    const int nparts = (NN + 255) / 256;   // 196
    scan1_kernel<<<nparts, 256, 0, stream>>>(counts, basearr, cursor);
    scan2_kernel<<<1, 256, 0, stream>>>(cursor, poff, nparts);
    hipMemsetAsync(cursor, 0, NN * sizeof(int), stream);
    scatter_kernel<<<(NE + 255) / 256, 256, 0, stream>>>(src, dst, basearr, poff,
                                                         cursor, eids, sidv, dstv);
    edge_agg_kernel<<<NE / 128, 256, 0, stream>>>(nhb, edge_h, eids, sidv, dstv,
                                                  Dg, We1t, S);
    node_kernel2<<<(NN + 127) / 128, 256, 0, stream>>>(nhb, S, counts,
                                                       We2t, be2, Wn1t, bn1,
                                                       Wn2t, bn2, (float*)d_out);
  } else {
    // fallback: R1 atomic path (ws >= ~25.9 MB)
    const size_t agg_bytes = (size_t)NN * DD * sizeof(float);
    float* agg = (float*)d_ws;
    char* wbase = ws + agg_bytes;
    __bf16* We1t = (__bf16*)(wbase);
    __bf16* We2t = (__bf16*)(wbase + 98304);
    __bf16* Wn1t = (__bf16*)(wbase + 98304 + 32768);
    __bf16* Wn2t = (__bf16*)(wbase + 98304 + 32768 + 65536);

    hipMemsetAsync(agg, 0, agg_bytes, stream);
    prep_kernel<<<(114688 + 255) / 256, 256, 0, stream>>>(We1, We2, Wn1, Wn2,
                                                          We1t, We2t, Wn1t, Wn2t);
    edge_fb_kernel<<<NE / 128, 256, 0, stream>>>(node_h, edge_h, src, dst,
                                                 We1t, be1, We2t, be2, agg);
    node_fb_kernel<<<(NN + 127) / 128, 256, 0, stream>>>(node_h, agg, Wn1t, bn1,
                                                         Wn2t, bn2, (float*)d_out);
  }
}

// Round 3
// 743.244 us; speedup vs baseline: 1.3283x; 1.1323x over previous
//
#include <hip/hip_runtime.h>

#define NN 50000
#define NE 640000
#define DD 128

typedef float f32x4 __attribute__((ext_vector_type(4)));
typedef __bf16 bf16x8 __attribute__((ext_vector_type(8)));
typedef unsigned short u16x8 __attribute__((ext_vector_type(8)));

__device__ inline __bf16 f2bf(float f) {
  unsigned u = __builtin_bit_cast(unsigned, f);
  u = (u + 0x7fffu + ((u >> 16) & 1u)) >> 16;
  unsigned short h = (unsigned short)u;
  return __builtin_bit_cast(__bf16, h);
}
__device__ inline unsigned short f2bfu(float f) {
  return __builtin_bit_cast(unsigned short, f2bf(f));
}
__device__ inline float bf2f(unsigned bits16) {
  return __builtin_bit_cast(float, bits16 << 16);
}
__device__ inline float bfval(__bf16 h) {
  return bf2f((unsigned)__builtin_bit_cast(unsigned short, h));
}

__device__ inline bf16x8 load8(const float* __restrict__ p) {
  f32x4 a = *(const f32x4*)p;
  f32x4 b = *(const f32x4*)(p + 4);
  bf16x8 o;
  o[0] = f2bf(a[0]); o[1] = f2bf(a[1]); o[2] = f2bf(a[2]); o[3] = f2bf(a[3]);
  o[4] = f2bf(b[0]); o[5] = f2bf(b[1]); o[6] = f2bf(b[2]); o[7] = f2bf(b[3]);
  return o;
}

#define MFMA16(a, b, c) __builtin_amdgcn_mfma_f32_16x16x32_bf16((a), (b), (c), 0, 0, 0)

// ======== K1: fused setup — conv_node + prep + hist + S-zero + cursor-zero ========
#define NB_CONV 3125   // 800000 / 256
#define NB_PREP 448    // 114688 / 256
#define NB_HIST 2500   // 640000 / 256
#define NB_SZ   1563   // 6,400,000 f32 / 4096 per block
#define NB_CZ   196    // 50176 ints
__global__ __launch_bounds__(256) void setup_kernel(
    const float* __restrict__ nh, unsigned short* __restrict__ nhb,
    const float* __restrict__ We1, const float* __restrict__ We2,
    const float* __restrict__ Wn1, const float* __restrict__ Wn2,
    __bf16* __restrict__ We1t, __bf16* __restrict__ We2t,
    __bf16* __restrict__ Wn1t, __bf16* __restrict__ Wn2t,
    const int* __restrict__ dst, int* __restrict__ counts,
    float* __restrict__ S, int* __restrict__ cursor) {
  const int b = (int)blockIdx.x;
  const int tid = (int)threadIdx.x;
  if (b < NB_CONV) {                       // node_h fp32 -> bf16
    int i = b * 256 + tid;
    const float* p = nh + (size_t)i * 8;
    f32x4 a = *(const f32x4*)p;
    f32x4 c = *(const f32x4*)(p + 4);
    u16x8 o;
    o[0] = f2bfu(a[0]); o[1] = f2bfu(a[1]); o[2] = f2bfu(a[2]); o[3] = f2bfu(a[3]);
    o[4] = f2bfu(c[0]); o[5] = f2bfu(c[1]); o[6] = f2bfu(c[2]); o[7] = f2bfu(c[3]);
    *(u16x8*)(nhb + (size_t)i * 8) = o;
  } else if (b < NB_CONV + NB_PREP) {      // weight transpose+convert
    int i = (b - NB_CONV) * 256 + tid;
    if (i < 49152) {
      int n = i / 384, k = i % 384;
      We1t[i] = f2bf(We1[k * 128 + n]);
    } else if (i < 65536) {
      int j = i - 49152; int n = j / 128, k = j % 128;
      We2t[j] = f2bf(We2[k * 128 + n]);
    } else if (i < 98304) {
      int j = i - 65536; int n = j / 256, k = j % 256;
      Wn1t[j] = f2bf(Wn1[k * 128 + n]);
    } else if (i < 114688) {
      int j = i - 98304; int n = j / 128, k = j % 128;
      Wn2t[j] = f2bf(Wn2[k * 128 + n]);
    }
  } else if (b < NB_CONV + NB_PREP + NB_HIST) {   // dst histogram
    int i = (b - NB_CONV - NB_PREP) * 256 + tid;
    if (i < NE) atomicAdd(&counts[dst[i]], 1);
  } else if (b < NB_CONV + NB_PREP + NB_HIST + NB_SZ) {  // zero S
    int fbase = (b - NB_CONV - NB_PREP - NB_HIST) * 4096 + tid * 16;
    if (fbase + 16 <= NN * DD) {
      f32x4 z = (f32x4){0.f, 0.f, 0.f, 0.f};
      f32x4* p = (f32x4*)(S + fbase);
      p[0] = z; p[1] = z; p[2] = z; p[3] = z;
    }
  } else {                                  // zero cursor
    int i = (b - NB_CONV - NB_PREP - NB_HIST - NB_SZ) * 256 + tid;
    if (i < NN) cursor[i] = 0;
  }
}

// ======== K2: fused scan1 + dnode ========
__global__ __launch_bounds__(256) void scan1_dnode_kernel(
    const int* __restrict__ counts, int* __restrict__ basearr,
    int* __restrict__ parts,
    const unsigned short* __restrict__ nhb, const __bf16* __restrict__ We1t,
    const float* __restrict__ be1, float* __restrict__ Dg) {
  const int b = (int)blockIdx.x;
  if (b < 196) {                            // scan1
    __shared__ int sd[256];
    int t = threadIdx.x;
    int i = b * 256 + t;
    int v = (i < NN) ? counts[i] : 0;
    sd[t] = v; __syncthreads();
    for (int off = 1; off < 256; off <<= 1) {
      int x = (t >= off) ? sd[t - off] : 0;
      __syncthreads();
      sd[t] += x;
      __syncthreads();
    }
    if (i < NN) basearr[i] = sd[t] - v;
    if (t == 255) parts[b] = sd[255];
    return;
  }
  // dnode: D[n] = nhb[n] @ We1[dst block] + be1 (fp32)
  const int tid = (int)threadIdx.x;
  const int w = tid >> 6;
  const int l = tid & 63;
  const int lm = l & 15;
  const int q = l >> 4;
  const int n0 = (b - 196) * 128;
  const int row0 = w * 32;

  int r0 = n0 + row0 + lm;
  int r1 = r0 + 16;
  int c0 = r0 < NN ? r0 : NN - 1;
  int c1 = r1 < NN ? r1 : NN - 1;

  f32x4 acc[2][8];
#pragma unroll
  for (int nt = 0; nt < 8; ++nt) {
    float bb = be1[nt * 16 + lm];
    acc[0][nt] = (f32x4){bb, bb, bb, bb};
    acc[1][nt] = (f32x4){bb, bb, bb, bb};
  }
#pragma unroll
  for (int s = 0; s < 4; ++s) {
    const int col = s * 32 + q * 8;
    bf16x8 a0 = __builtin_bit_cast(bf16x8, *(const u16x8*)(nhb + (size_t)c0 * DD + col));
    bf16x8 a1 = __builtin_bit_cast(bf16x8, *(const u16x8*)(nhb + (size_t)c1 * DD + col));
    const __bf16* bp = We1t + (size_t)lm * 384 + 128 + s * 32 + q * 8;
#pragma unroll
    for (int nt = 0; nt < 8; ++nt) {
      bf16x8 bb = *(const bf16x8*)(bp + nt * 16 * 384);
      acc[0][nt] = MFMA16(a0, bb, acc[0][nt]);
      acc[1][nt] = MFMA16(a1, bb, acc[1][nt]);
    }
  }
#pragma unroll
  for (int t = 0; t < 2; ++t) {
#pragma unroll
    for (int r = 0; r < 4; ++r) {
      int node = n0 + row0 + t * 16 + q * 4 + r;
      if (node < NN) {
        float* orow = Dg + (size_t)node * DD + lm;
#pragma unroll
        for (int nt = 0; nt < 8; ++nt)
          orow[nt * 16] = acc[t][nt][r];
      }
    }
  }
}

// ======== K3: scan2 ========
__global__ void scan2_kernel(const int* __restrict__ parts, int* __restrict__ poff,
                             int nparts) {
  __shared__ int sd[256];
  int t = threadIdx.x;
  int v = (t < nparts) ? parts[t] : 0;
  sd[t] = v; __syncthreads();
  for (int off = 1; off < 256; off <<= 1) {
    int x = (t >= off) ? sd[t - off] : 0;
    __syncthreads();
    sd[t] += x;
    __syncthreads();
  }
  if (t < nparts) poff[t] = sd[t] - v;
}

// ======== K4: scatter (folds scan3's poff add) ========
__global__ void scatter_kernel(const int* __restrict__ src, const int* __restrict__ dst,
                               const int* __restrict__ basearr, const int* __restrict__ poff,
                               int* __restrict__ cursor, int* __restrict__ eids,
                               int* __restrict__ sidv, int* __restrict__ dstv) {
  int i = blockIdx.x * 256 + threadIdx.x;
  if (i < NE) {
    int d = dst[i];
    int p = basearr[d] + poff[d >> 8] + atomicAdd(&cursor[d], 1);
    eids[p] = i;
    sidv[p] = src[i];
    dstv[p] = d;
  }
}

// ======== K5: edge MLP layer-1 (K=256, LDS-staged B) + fused segment-sum ========
// B (We1t slices) staged into LDS in two 32KB phases (edge block, src block),
// XOR-swizzled for conflict-free ds_read_b128. The h1 / Dlds buffers overlay
// the B region (B dead before they're written). dst-block folded via Dg.
__device__ inline void stageB(unsigned short* lds16, const __bf16* __restrict__ We1t,
                              int kbase, int tid) {
  const int n = tid >> 1;
  const int colb = (tid & 1) * 128;
  const unsigned short* srcrow = (const unsigned short*)We1t + (size_t)n * 384 + kbase;
  char* dstrow = (char*)lds16 + n * 256;
  const int sw = (n & 15) << 4;
#pragma unroll
  for (int j = 0; j < 8; ++j) {
    int cb = colb + j * 16;
    u16x8 v = *(const u16x8*)(srcrow + cb / 2);
    *(u16x8*)(dstrow + (cb ^ sw)) = v;
  }
}

__global__ __launch_bounds__(256) void edge_agg_kernel(
    const unsigned short* __restrict__ nhb, const float* __restrict__ edge_h,
    const int* __restrict__ eids, const int* __restrict__ sidv,
    const int* __restrict__ dstv, const float* __restrict__ Dg,
    const __bf16* __restrict__ We1t, float* __restrict__ S) {
  __shared__ unsigned short lds16[128 * 136];   // B-stage (32K) / Dlds (33K) / h1 (34.8K)
  __shared__ int dloc[128];
  __shared__ int sidx[128];
  __shared__ int segdst[128];
  __shared__ int wcnt0s, nsegS;

  const int tid = (int)threadIdx.x;
  const int w = tid >> 6;
  const int l = tid & 63;
  const int lm = l & 15;
  const int q = l >> 4;
  const int e0 = (int)blockIdx.x * 128;
  const int row0 = w * 32;
  const int p0 = e0 + row0 + lm;
  const int p1 = p0 + 16;

  const float* ehp0 = edge_h + (size_t)eids[p0] * DD;
  const float* ehp1 = edge_h + (size_t)eids[p1] * DD;
  const unsigned short* sp0 = nhb + (size_t)sidv[p0] * DD;
  const unsigned short* sp1 = nhb + (size_t)sidv[p1] * DD;

  // ---- prefetch all A operands (HBM edge_h first, then L2/L3 nhb) ----
  bf16x8 ea0[4], ea1[4];
#pragma unroll
  for (int s = 0; s < 4; ++s) {
    ea0[s] = load8(ehp0 + s * 32 + q * 8);
    ea1[s] = load8(ehp1 + s * 32 + q * 8);
  }
  u16x8 sa0[4], sa1[4];
#pragma unroll
  for (int s = 0; s < 4; ++s) {
    sa0[s] = *(const u16x8*)(sp0 + s * 32 + q * 8);
    sa1[s] = *(const u16x8*)(sp1 + s * 32 + q * 8);
  }

  // ---- segment-index scan over the 128 tile rows (waves 0,1) ----
  int d = 0, flag = 0, idx = 0;
  if (tid < 128) {
    d = dstv[e0 + tid];
    dloc[tid] = d;
    int dp = (tid == 0) ? -1 : dstv[e0 + tid - 1];
    flag = (d != dp) ? 1 : 0;
    unsigned long long mask = __ballot(flag);
    idx = (int)__popcll(mask & ((1ull << (tid & 63)) - 1)) + flag - 1;
    if (tid == 63) wcnt0s = (int)__popcll(mask);
  }
  __syncthreads();                                   // (1)
  if (tid < 128) {
    if (tid >= 64) idx += wcnt0s;
    sidx[tid] = idx;
    if (flag) segdst[idx] = d;
    if (tid == 127) nsegS = idx + 1;
  }
  stageB(lds16, We1t, 256, tid);                     // B: edge block
  __syncthreads();                                   // (2)

  f32x4 acc[2][8];
#pragma unroll
  for (int nt = 0; nt < 8; ++nt) {
    acc[0][nt] = (f32x4){0.f, 0.f, 0.f, 0.f};
    acc[1][nt] = (f32x4){0.f, 0.f, 0.f, 0.f};
  }
  const char* Bb = (const char*)lds16;
  const int swr = lm << 4;

  // ---- K-loop phase 1: edge_h rows ----
#pragma unroll
  for (int s = 0; s < 4; ++s) {
#pragma unroll
    for (int nt = 0; nt < 8; ++nt) {
      bf16x8 bb = *(const bf16x8*)(Bb + (nt * 16 + lm) * 256 + ((s * 64 + q * 16) ^ swr));
      acc[0][nt] = MFMA16(ea0[s], bb, acc[0][nt]);
      acc[1][nt] = MFMA16(ea1[s], bb, acc[1][nt]);
    }
  }
  __syncthreads();                                   // (3)
  stageB(lds16, We1t, 0, tid);                       // B: src block
  __syncthreads();                                   // (4)

  // ---- K-loop phase 2: src-h gathers ----
#pragma unroll
  for (int s = 0; s < 4; ++s) {
    bf16x8 a0 = __builtin_bit_cast(bf16x8, sa0[s]);
    bf16x8 a1 = __builtin_bit_cast(bf16x8, sa1[s]);
#pragma unroll
    for (int nt = 0; nt < 8; ++nt) {
      bf16x8 bb = *(const bf16x8*)(Bb + (nt * 16 + lm) * 256 + ((s * 64 + q * 16) ^ swr));
      acc[0][nt] = MFMA16(a0, bb, acc[0][nt]);
      acc[1][nt] = MFMA16(a1, bb, acc[1][nt]);
    }
  }
  __syncthreads();                                   // (5) B dead

  // ---- stage distinct D rows into LDS (overlay) ----
  const int nsegT = nsegS;
  float* Dlds = (float*)lds16;
  {
    const int nstage = nsegT < 64 ? nsegT : 64;
    const int total = nstage << 7;
    for (int base = 0; base < total; base += 1024) {
      float v[4];
#pragma unroll
      for (int u = 0; u < 4; ++u) {
        int i = base + u * 256 + tid;
        if (i < total) v[u] = Dg[(size_t)segdst[i >> 7] * DD + (i & 127)];
      }
#pragma unroll
      for (int u = 0; u < 4; ++u) {
        int i = base + u * 256 + tid;
        if (i < total) Dlds[(i >> 7) * 129 + (i & 127)] = v[u];
      }
    }
  }
  __syncthreads();                                   // (6)

  // ---- add D (dst contribution + be1), relu ----
  if (nsegT <= 64) {
#pragma unroll
    for (int t = 0; t < 2; ++t)
#pragma unroll
      for (int r = 0; r < 4; ++r) {
        int row = row0 + t * 16 + q * 4 + r;
        int si = sidx[row];
#pragma unroll
        for (int nt = 0; nt < 8; ++nt) {
          float v = acc[t][nt][r] + Dlds[si * 129 + nt * 16 + lm];
          acc[t][nt][r] = v > 0.f ? v : 0.f;
        }
      }
  } else {
#pragma unroll
    for (int t = 0; t < 2; ++t)
#pragma unroll
      for (int r = 0; r < 4; ++r) {
        int row = row0 + t * 16 + q * 4 + r;
        const float* drow = Dg + (size_t)dloc[row] * DD + lm;
#pragma unroll
        for (int nt = 0; nt < 8; ++nt) {
          float v = acc[t][nt][r] + drow[nt * 16];
          acc[t][nt][r] = v > 0.f ? v : 0.f;
        }
      }
  }
  __syncthreads();                                   // (7) Dlds dead

  // ---- relu tile -> h1 (bf16, row-major) ----
#pragma unroll
  for (int t = 0; t < 2; ++t)
#pragma unroll
    for (int nt = 0; nt < 8; ++nt)
#pragma unroll
      for (int r = 0; r < 4; ++r) {
        int m = row0 + t * 16 + q * 4 + r;
        lds16[m * 136 + nt * 16 + lm] = f2bfu(acc[t][nt][r]);
      }
  __syncthreads();                                   // (8)

  // ---- segmented column reduction -> coalesced fp32 atomics into S ----
  {
    const int col = tid & 127;
    const int rbeg = (tid >> 7) * 64;
    const int rend = rbeg + 64;
    float a = 0.f;
    int dcur = dloc[rbeg];
    for (int r = rbeg; r < rend; ++r) {
      int dd = dloc[r];
      if (dd != dcur) {
        unsafeAtomicAdd(&S[(size_t)dcur * DD + col], a);
        a = 0.f;
        dcur = dd;
      }
      a += bf2f((unsigned)lds16[r * 136 + col]);
    }
    unsafeAtomicAdd(&S[(size_t)dcur * DD + col], a);
  }
}

// ======== K6: node side — agg_m = S@We2 + cnt*be2 (split), node MLP ========
__global__ __launch_bounds__(256) void node_kernel2(
    const unsigned short* __restrict__ nhb, const float* __restrict__ S,
    const int* __restrict__ counts,
    const __bf16* __restrict__ We2t, const float* __restrict__ be2,
    const __bf16* __restrict__ Wn1t, const float* __restrict__ bn1,
    const __bf16* __restrict__ Wn2t, const float* __restrict__ bn2,
    float* __restrict__ out) {
  __shared__ unsigned short h1[128 * 136];
  const int tid = (int)threadIdx.x;
  const int w = tid >> 6;
  const int l = tid & 63;
  const int lm = l & 15;
  const int q = l >> 4;
  const int n0 = (int)blockIdx.x * 128;
  const int row0 = w * 32;

  int r0 = n0 + row0 + lm;
  int r1 = r0 + 16;
  int c0 = r0 < NN ? r0 : NN - 1;
  int c1 = r1 < NN ? r1 : NN - 1;
  const float* s0p = S + (size_t)c0 * DD;
  const float* s1p = S + (size_t)c1 * DD;

  f32x4 acc[2][8];

  // ---- stage A: acc = cnt*be2 + S @ We2 (bf16 hi/lo split, K doubled) ----
  {
    float cnt0[4], cnt1[4];
#pragma unroll
    for (int r = 0; r < 4; ++r) {
      int ra = n0 + row0 + q * 4 + r;
      int rb = ra + 16;
      cnt0[r] = (ra < NN) ? (float)counts[ra] : 0.f;
      cnt1[r] = (rb < NN) ? (float)counts[rb] : 0.f;
    }
#pragma unroll
    for (int nt = 0; nt < 8; ++nt) {
      float b = be2[nt * 16 + lm];
#pragma unroll
      for (int r = 0; r < 4; ++r) {
        acc[0][nt][r] = cnt0[r] * b;
        acc[1][nt][r] = cnt1[r] * b;
      }
    }
  }
#pragma unroll
  for (int step = 0; step < 4; ++step) {
    const int col = step * 32 + q * 8;
    f32x4 x0a = *(const f32x4*)(s0p + col);
    f32x4 x0b = *(const f32x4*)(s0p + col + 4);
    f32x4 x1a = *(const f32x4*)(s1p + col);
    f32x4 x1b = *(const f32x4*)(s1p + col + 4);
    bf16x8 h0, l0, h8, l8;
#pragma unroll
    for (int j = 0; j < 4; ++j) {
      float v = x0a[j]; __bf16 hh = f2bf(v);
      h0[j] = hh; l0[j] = f2bf(v - bfval(hh));
      v = x0b[j]; hh = f2bf(v);
      h0[j + 4] = hh; l0[j + 4] = f2bf(v - bfval(hh));
      v = x1a[j]; hh = f2bf(v);
      h8[j] = hh; l8[j] = f2bf(v - bfval(hh));
      v = x1b[j]; hh = f2bf(v);
      h8[j + 4] = hh; l8[j + 4] = f2bf(v - bfval(hh));
    }
    const __bf16* bp = We2t + (size_t)lm * 128 + step * 32 + q * 8;
#pragma unroll
    for (int nt = 0; nt < 8; ++nt) {
      bf16x8 bb = *(const bf16x8*)(bp + nt * 16 * 128);
      acc[0][nt] = MFMA16(h0, bb, acc[0][nt]);
      acc[0][nt] = MFMA16(l0, bb, acc[0][nt]);
      acc[1][nt] = MFMA16(h8, bb, acc[1][nt]);
      acc[1][nt] = MFMA16(l8, bb, acc[1][nt]);
    }
  }

#pragma unroll
  for (int t = 0; t < 2; ++t)
#pragma unroll
    for (int nt = 0; nt < 8; ++nt)
#pragma unroll
      for (int r = 0; r < 4; ++r) {
        int m = row0 + t * 16 + q * 4 + r;
        h1[m * 136 + nt * 16 + lm] = f2bfu(acc[t][nt][r]);
      }
  __syncthreads();

  // ---- stage B: relu(concat(agg_m, node_h) @ Wn1 + bn1), K = 256 ----
#pragma unroll
  for (int nt = 0; nt < 8; ++nt) {
    float b = bn1[nt * 16 + lm];
    acc[0][nt] = (f32x4){b, b, b, b};
    acc[1][nt] = (f32x4){b, b, b, b};
  }
#pragma unroll
  for (int step = 0; step < 8; ++step) {
    bf16x8 a0, a1;
    if (step < 4) {
      a0 = __builtin_bit_cast(bf16x8, *(const u16x8*)&h1[(row0 + lm) * 136 + step * 32 + q * 8]);
      a1 = __builtin_bit_cast(bf16x8, *(const u16x8*)&h1[(row0 + 16 + lm) * 136 + step * 32 + q * 8]);
    } else {
      const int col = (step - 4) * 32 + q * 8;
      a0 = __builtin_bit_cast(bf16x8, *(const u16x8*)(nhb + (size_t)c0 * DD + col));
      a1 = __builtin_bit_cast(bf16x8, *(const u16x8*)(nhb + (size_t)c1 * DD + col));
    }
    const __bf16* bp = Wn1t + (size_t)lm * 256 + step * 32 + q * 8;
#pragma unroll
    for (int nt = 0; nt < 8; ++nt) {
      bf16x8 bb = *(const bf16x8*)(bp + nt * 16 * 256);
      acc[0][nt] = MFMA16(a0, bb, acc[0][nt]);
      acc[1][nt] = MFMA16(a1, bb, acc[1][nt]);
    }
  }
  __syncthreads();

#pragma unroll
  for (int t = 0; t < 2; ++t)
#pragma unroll
    for (int nt = 0; nt < 8; ++nt)
#pragma unroll
      for (int r = 0; r < 4; ++r) {
        float v = acc[t][nt][r];
        v = v > 0.f ? v : 0.f;
        int m = row0 + t * 16 + q * 4 + r;
        h1[m * 136 + nt * 16 + lm] = f2bfu(v);
      }
  __syncthreads();

  // ---- stage C: h1 @ Wn2 + bn2, K = 128 ----
#pragma unroll
  for (int nt = 0; nt < 8; ++nt) {
    float b = bn2[nt * 16 + lm];
    acc[0][nt] = (f32x4){b, b, b, b};
    acc[1][nt] = (f32x4){b, b, b, b};
  }
#pragma unroll
  for (int step = 0; step < 4; ++step) {
    bf16x8 a0 = __builtin_bit_cast(bf16x8, *(const u16x8*)&h1[(row0 + lm) * 136 + step * 32 + q * 8]);
    bf16x8 a1 = __builtin_bit_cast(bf16x8, *(const u16x8*)&h1[(row0 + 16 + lm) * 136 + step * 32 + q * 8]);
    const __bf16* bp = Wn2t + (size_t)lm * 128 + step * 32 + q * 8;
#pragma unroll
    for (int nt = 0; nt < 8; ++nt) {
      bf16x8 bb = *(const bf16x8*)(bp + nt * 16 * 128);
      acc[0][nt] = MFMA16(a0, bb, acc[0][nt]);
      acc[1][nt] = MFMA16(a1, bb, acc[1][nt]);
    }
  }

#pragma unroll
  for (int t = 0; t < 2; ++t) {
#pragma unroll
    for (int r = 0; r < 4; ++r) {
      int node = n0 + row0 + t * 16 + q * 4 + r;
      if (node < NN) {
        float* orow = out + (size_t)node * DD + lm;
#pragma unroll
        for (int nt = 0; nt < 8; ++nt)
          orow[nt * 16] = acc[t][nt][r];
      }
    }
  }
}

// ======================= fallback (R1 atomic path) =======================
__global__ void prep_fb_kernel(const float* __restrict__ We1, const float* __restrict__ We2,
                               const float* __restrict__ Wn1, const float* __restrict__ Wn2,
                               __bf16* __restrict__ We1t, __bf16* __restrict__ We2t,
                               __bf16* __restrict__ Wn1t, __bf16* __restrict__ Wn2t) {
  int i = blockIdx.x * blockDim.x + threadIdx.x;
  if (i < 49152) {
    int n = i / 384, k = i % 384;
    We1t[i] = f2bf(We1[k * 128 + n]);
  } else if (i < 65536) {
    int j = i - 49152; int n = j / 128, k = j % 128;
    We2t[j] = f2bf(We2[k * 128 + n]);
  } else if (i < 98304) {
    int j = i - 65536; int n = j / 256, k = j % 256;
    Wn1t[j] = f2bf(Wn1[k * 128 + n]);
  } else if (i < 114688) {
    int j = i - 98304; int n = j / 128, k = j % 128;
    Wn2t[j] = f2bf(Wn2[k * 128 + n]);
  }
}

__global__ __launch_bounds__(256) void edge_fb_kernel(
    const float* __restrict__ node_h, const float* __restrict__ edge_h,
    const int* __restrict__ src, const int* __restrict__ dst,
    const __bf16* __restrict__ We1t, const float* __restrict__ be1,
    const __bf16* __restrict__ We2t, const float* __restrict__ be2,
    float* __restrict__ agg) {
  __shared__ unsigned short h1[128 * 136];
  const int tid = (int)threadIdx.x;
  const int w = tid >> 6;
  const int l = tid & 63;
  const int lm = l & 15;
  const int q = l >> 4;
  const int e0 = (int)blockIdx.x * 128;
  const int row0 = w * 32;

  const int eA0 = e0 + row0 + lm;
  const int eA1 = eA0 + 16;
  const float* srcA0[3];
  const float* srcA1[3];
  srcA0[0] = node_h + (size_t)src[eA0] * DD;
  srcA0[1] = node_h + (size_t)dst[eA0] * DD;
  srcA0[2] = edge_h + (size_t)eA0 * DD;
  srcA1[0] = node_h + (size_t)src[eA1] * DD;
  srcA1[1] = node_h + (size_t)dst[eA1] * DD;
  srcA1[2] = edge_h + (size_t)eA1 * DD;

  f32x4 acc[2][8];
#pragma unroll
  for (int nt = 0; nt < 8; ++nt) {
    float b = be1[nt * 16 + lm];
    acc[0][nt] = (f32x4){b, b, b, b};
    acc[1][nt] = (f32x4){b, b, b, b};
  }
#pragma unroll
  for (int step = 0; step < 12; ++step) {
    const int region = step >> 2;
    const int col = ((step & 3) * 32) + q * 8;
    bf16x8 a0 = load8(srcA0[region] + col);
    bf16x8 a1 = load8(srcA1[region] + col);
    const __bf16* bp = We1t + (size_t)lm * 384 + step * 32 + q * 8;
#pragma unroll
    for (int nt = 0; nt < 8; ++nt) {
      bf16x8 bb = *(const bf16x8*)(bp + nt * 16 * 384);
      acc[0][nt] = MFMA16(a0, bb, acc[0][nt]);
      acc[1][nt] = MFMA16(a1, bb, acc[1][nt]);
    }
  }
#pragma unroll
  for (int t = 0; t < 2; ++t)
#pragma unroll
    for (int nt = 0; nt < 8; ++nt)
#pragma unroll
      for (int r = 0; r < 4; ++r) {
        float v = acc[t][nt][r];
        v = v > 0.f ? v : 0.f;
        int m = row0 + t * 16 + q * 4 + r;
        h1[m * 136 + nt * 16 + lm] = f2bfu(v);
      }
  __syncthreads();
#pragma unroll
  for (int nt = 0; nt < 8; ++nt) {
    float b = be2[nt * 16 + lm];
    acc[0][nt] = (f32x4){b, b, b, b};
    acc[1][nt] = (f32x4){b, b, b, b};
  }
#pragma unroll
  for (int step = 0; step < 4; ++step) {
    bf16x8 a0 = __builtin_bit_cast(bf16x8, *(const u16x8*)&h1[(row0 + lm) * 136 + step * 32 + q * 8]);
    bf16x8 a1 = __builtin_bit_cast(bf16x8, *(const u16x8*)&h1[(row0 + 16 + lm) * 136 + step * 32 + q * 8]);
    const __bf16* bp = We2t + (size_t)lm * 128 + step * 32 + q * 8;
#pragma unroll
    for (int nt = 0; nt < 8; ++nt) {
      bf16x8 bb = *(const bf16x8*)(bp + nt * 16 * 128);
      acc[0][nt] = MFMA16(a0, bb, acc[0][nt]);
      acc[1][nt] = MFMA16(a1, bb, acc[1][nt]);
    }
  }
#pragma unroll
  for (int t = 0; t < 2; ++t) {
#pragma unroll
    for (int r = 0; r < 4; ++r) {
      int e = e0 + row0 + t * 16 + q * 4 + r;
      float* arow = agg + (size_t)dst[e] * DD + lm;
#pragma unroll
      for (int nt = 0; nt < 8; ++nt)
        unsafeAtomicAdd(arow + nt * 16, acc[t][nt][r]);
    }
  }
}

__global__ __launch_bounds__(256) void node_fb_kernel(
    const float* __restrict__ node_h, const float* __restrict__ agg,
    const __bf16* __restrict__ Wn1t, const float* __restrict__ bn1,
    const __bf16* __restrict__ Wn2t, const float* __restrict__ bn2,
    float* __restrict__ out) {
  __shared__ unsigned short h1[128 * 136];
  const int tid = (int)threadIdx.x;
  const int w = tid >> 6;
  const int l = tid & 63;
  const int lm = l & 15;
  const int q = l >> 4;
  const int n0 = (int)blockIdx.x * 128;
  const int row0 = w * 32;

  int r0 = n0 + row0 + lm;
  int r1 = r0 + 16;
  int c0 = r0 < NN ? r0 : NN - 1;
  int c1 = r1 < NN ? r1 : NN - 1;
  const float* srcA0[2] = {agg + (size_t)c0 * DD, node_h + (size_t)c0 * DD};
  const float* srcA1[2] = {agg + (size_t)c1 * DD, node_h + (size_t)c1 * DD};

  f32x4 acc[2][8];
#pragma unroll
  for (int nt = 0; nt < 8; ++nt) {
    float b = bn1[nt * 16 + lm];
    acc[0][nt] = (f32x4){b, b, b, b};
    acc[1][nt] = (f32x4){b, b, b, b};
  }
#pragma unroll
  for (int step = 0; step < 8; ++step) {
    const int region = step >> 2;
    const int col = ((step & 3) * 32) + q * 8;
    bf16x8 a0 = load8(srcA0[region] + col);
    bf16x8 a1 = load8(srcA1[region] + col);
    const __bf16* bp = Wn1t + (size_t)lm * 256 + step * 32 + q * 8;
#pragma unroll
    for (int nt = 0; nt < 8; ++nt) {
      bf16x8 bb = *(const bf16x8*)(bp + nt * 16 * 256);
      acc[0][nt] = MFMA16(a0, bb, acc[0][nt]);
      acc[1][nt] = MFMA16(a1, bb, acc[1][nt]);
    }
  }
#pragma unroll
  for (int t = 0; t < 2; ++t)
#pragma unroll
    for (int nt = 0; nt < 8; ++nt)
#pragma unroll
      for (int r = 0; r < 4; ++r) {
        float v = acc[t][nt][r];
        v = v > 0.f ? v : 0.f;
        int m = row0 + t * 16 + q * 4 + r;
        h1[m * 136 + nt * 16 + lm] = f2bfu(v);
      }
  __syncthreads();
#pragma unroll
  for (int nt = 0; nt < 8; ++nt) {
    float b = bn2[nt * 16 + lm];
    acc[0][nt] = (f32x4){b, b, b, b};
    acc[1][nt] = (f32x4){b, b, b, b};
  }
#pragma unroll
  for (int step = 0; step < 4; ++step) {
    bf16x8 a0 = __builtin_bit_cast(bf16x8, *(const u16x8*)&h1[(row0 + lm) * 136 + step * 32 + q * 8]);
    bf16x8 a1 = __builtin_bit_cast(bf16x8, *(const u16x8*)&h1[(row0 + 16 + lm) * 136 + step * 32 + q * 8]);
    const __bf16* bp = Wn2t + (size_t)lm * 128 + step * 32 + q * 8;
#pragma unroll
    for (int nt = 0; nt < 8; ++nt) {
      bf16x8 bb = *(const bf16x8*)(bp + nt * 16 * 128);
      acc[0][nt] = MFMA16(a0, bb, acc[0][nt]);
      acc[1][nt] = MFMA16(a1, bb, acc[1][nt]);
    }
  }
#pragma unroll
  for (int t = 0; t < 2; ++t) {
#pragma unroll
    for (int r = 0; r < 4; ++r) {
      int node = n0 + row0 + t * 16 + q * 4 + r;
      if (node < NN) {
        float* orow = out + (size_t)node * DD + lm;
#pragma unroll
        for (int nt = 0; nt < 8; ++nt)
          orow[nt * 16] = acc[t][nt][r];
      }
    }
  }
}

extern "C" void kernel_launch(void* const* d_in, const int* in_sizes, int n_in,
                              void* d_out, int out_size, void* d_ws, size_t ws_size,
                              hipStream_t stream) {
  const float* node_h = (const float*)d_in[0];
  const float* edge_h = (const float*)d_in[1];
  const int* src = (const int*)d_in[2];
  const int* dst = (const int*)d_in[3];
  const float* We1 = (const float*)d_in[4];
  const float* be1 = (const float*)d_in[5];
  const float* We2 = (const float*)d_in[6];
  const float* be2 = (const float*)d_in[7];
  const float* Wn1 = (const float*)d_in[8];
  const float* bn1 = (const float*)d_in[9];
  const float* Wn2 = (const float*)d_in[10];
  const float* bn2 = (const float*)d_in[11];

  // CSR-path ws layout (bytes)
  const size_t o_S    = 0;                    //  25,600,000  fp32 segment sums
  const size_t o_D    = 25600000;             //  25,600,000  fp32 dst-precompute
  const size_t o_nhb  = 51200000;             //  12,800,000
  const size_t o_we1  = 64000000;             //      98,304
  const size_t o_we2  = 64098304;             //      32,768
  const size_t o_wn1  = 64131072;             //      65,536
  const size_t o_wn2  = 64196608;             //      32,768
  const size_t o_cnt  = 64229376;             //     200,000
  const size_t o_base = 64429376;             //     200,000
  const size_t o_cur  = 64629376;             //     200,000
  const size_t o_poff = 64829376;             //       1,024
  const size_t o_eids = 64830400;             //   2,560,000
  const size_t o_sidv = 67390400;             //   2,560,000
  const size_t o_dstv = 69950400;             //   2,560,000
  const size_t o_part = 72510400;             //       1,024
  const size_t csr_need = 72511424;

  char* ws = (char*)d_ws;

  if (ws_size >= csr_need) {
    float* S     = (float*)(ws + o_S);
    float* Dg    = (float*)(ws + o_D);
    unsigned short* nhb = (unsigned short*)(ws + o_nhb);
    __bf16* We1t = (__bf16*)(ws + o_we1);
    __bf16* We2t = (__bf16*)(ws + o_we2);
    __bf16* Wn1t = (__bf16*)(ws + o_wn1);
    __bf16* Wn2t = (__bf16*)(ws + o_wn2);
    int* counts  = (int*)(ws + o_cnt);
    int* basearr = (int*)(ws + o_base);
    int* cursor  = (int*)(ws + o_cur);
    int* poff    = (int*)(ws + o_poff);
    int* eids    = (int*)(ws + o_eids);
    int* sidv    = (int*)(ws + o_sidv);
    int* dstv    = (int*)(ws + o_dstv);
    int* parts   = (int*)(ws + o_part);

    hipMemsetAsync(counts, 0, NN * sizeof(int), stream);
    const int nb_setup = NB_CONV + NB_PREP + NB_HIST + NB_SZ + NB_CZ;
    setup_kernel<<<nb_setup, 256, 0, stream>>>(node_h, nhb, We1, We2, Wn1, Wn2,
                                               We1t, We2t, Wn1t, Wn2t,
                                               dst, counts, S, cursor);
    scan1_dnode_kernel<<<196 + 391, 256, 0, stream>>>(counts, basearr, parts,
                                                      nhb, We1t, be1, Dg);
    scan2_kernel<<<1, 256, 0, stream>>>(parts, poff, 196);
    scatter_kernel<<<(NE + 255) / 256, 256, 0, stream>>>(src, dst, basearr, poff,
                                                         cursor, eids, sidv, dstv);
    edge_agg_kernel<<<NE / 128, 256, 0, stream>>>(nhb, edge_h, eids, sidv, dstv,
                                                  Dg, We1t, S);
    node_kernel2<<<(NN + 127) / 128, 256, 0, stream>>>(nhb, S, counts,
                                                       We2t, be2, Wn1t, bn1,
                                                       Wn2t, bn2, (float*)d_out);
  } else {
    // fallback: R1 atomic path (ws >= ~25.9 MB)
    const size_t agg_bytes = (size_t)NN * DD * sizeof(float);
    float* agg = (float*)d_ws;
    char* wbase = ws + agg_bytes;
    __bf16* We1t = (__bf16*)(wbase);
    __bf16* We2t = (__bf16*)(wbase + 98304);
    __bf16* Wn1t = (__bf16*)(wbase + 98304 + 32768);
    __bf16* Wn2t = (__bf16*)(wbase + 98304 + 32768 + 65536);

    hipMemsetAsync(agg, 0, agg_bytes, stream);
    prep_fb_kernel<<<(114688 + 255) / 256, 256, 0, stream>>>(We1, We2, Wn1, Wn2,
                                                             We1t, We2t, Wn1t, Wn2t);
    edge_fb_kernel<<<NE / 128, 256, 0, stream>>>(node_h, edge_h, src, dst,
                                                 We1t, be1, We2t, be2, agg);
    node_fb_kernel<<<(NN + 127) / 128, 256, 0, stream>>>(node_h, agg, Wn1t, bn1,
                                                         Wn2t, bn2, (float*)d_out);
  }
}